// Round 4
// baseline (1189.760 us; speedup 1.0000x reference)
//
#include <hip/hip_runtime.h>
#include <hip/hip_bf16.h>
#include <math.h>

#define EMB  2048
#define NH   16
#define HD   128
#define SEQ  2048
#define BATCH 2
#define MTOK (BATCH*SEQ)   // 4096 tokens

using bf16x8 = __attribute__((ext_vector_type(8))) __bf16;
using f32x4  = __attribute__((ext_vector_type(4))) float;

__device__ __forceinline__ unsigned short f2bf(float x) {
    unsigned int u = __float_as_uint(x);
    u += 0x7fffu + ((u >> 16) & 1u);   // round-to-nearest-even
    return (unsigned short)(u >> 16);
}

__device__ __forceinline__ float gelu_exact(float x) {
    return 0.5f * x * (1.0f + erff(x * 0.70710678118654752f));
}

// ---------------- flat f32 -> bf16 convert (4 elems/thread) ----------------
__global__ __launch_bounds__(256) void k_conv(const float* __restrict__ in,
                                              unsigned short* __restrict__ out, int n4) {
    int i = blockIdx.x * 256 + threadIdx.x;
    if (i >= n4) return;
    float4 v = ((const float4*)in)[i];
    ushort4 o;
    o.x = f2bf(v.x); o.y = f2bf(v.y); o.z = f2bf(v.z); o.w = f2bf(v.w);
    ((ushort4*)out)[i] = o;
}

// ------------- W[K][N] f32 -> Wt[N][K] bf16 (tiled transpose) ---------------
__global__ __launch_bounds__(256) void k_transconv(const float* __restrict__ W,
                                                   unsigned short* __restrict__ Wt,
                                                   int K, int N) {
    __shared__ float t[32][33];
    int tx = threadIdx.x & 31, ty = threadIdx.x >> 5;   // 32 x 8
    int c0 = blockIdx.x * 32, r0 = blockIdx.y * 32;
    #pragma unroll
    for (int i = 0; i < 4; ++i)
        t[ty + i*8][tx] = W[(size_t)(r0 + ty + i*8) * N + c0 + tx];
    __syncthreads();
    #pragma unroll
    for (int i = 0; i < 4; ++i)
        Wt[(size_t)(c0 + ty + i*8) * K + r0 + tx] = f2bf(t[tx][ty + i*8]);
}

// ---------------- bf16 MFMA GEMM: C = A[M,K] @ Bt[N,K]^T + bias -------------
// EPI: 0=f32 out; 1=f32 out + residual; 2=bf16 GELU out; 3=bf16 out;
//      4=bf16 out transposed per-head -> VT[(b*NH+h)*HD + d][SEQ]
template<int EPI>
__global__ __launch_bounds__(256) void k_gemm(const unsigned short* __restrict__ A,
                                              const unsigned short* __restrict__ Bt,
                                              const float* __restrict__ bias,
                                              const float* __restrict__ res,
                                              void* __restrict__ Cout,
                                              int M, int N, int K) {
    __shared__ unsigned short As[128 * 32];
    __shared__ unsigned short Bs[128 * 32];
    const int tid = threadIdx.x;
    const int lane = tid & 63, wid = tid >> 6;
    const int wm = wid >> 1, wn = wid & 1;            // 2x2 waves, 64x64 each
    const int bm = blockIdx.x, bn = blockIdx.y;
    f32x4 acc[4][4] = {};
    const int srow = wid * 16 + (lane >> 2);          // staging row within 64-row half
    const int scol = (lane & 3) * 8;                  // staging col (8 bf16 = 16B)
    const unsigned short* Ab = A  + (size_t)bm * 128 * K;
    const unsigned short* Bb = Bt + (size_t)bn * 128 * K;

    for (int kt = 0; kt < K; kt += 32) {
        #pragma unroll
        for (int i = 0; i < 2; ++i) {
            const unsigned short* ga = Ab + (size_t)(i*64 + srow) * K + kt + scol;
            const unsigned short* gb = Bb + (size_t)(i*64 + srow) * K + kt + scol;
            __builtin_amdgcn_global_load_lds(
                (const __attribute__((address_space(1))) void*)ga,
                (__attribute__((address_space(3))) void*)&As[(i*64 + wid*16) * 32], 16, 0, 0);
            __builtin_amdgcn_global_load_lds(
                (const __attribute__((address_space(1))) void*)gb,
                (__attribute__((address_space(3))) void*)&Bs[(i*64 + wid*16) * 32], 16, 0, 0);
        }
        __syncthreads();

        bf16x8 af[4], bfr[4];
        #pragma unroll
        for (int mi = 0; mi < 4; ++mi)
            af[mi] = *(const bf16x8*)&As[(wm*64 + mi*16 + (lane & 15)) * 32 + (lane >> 4) * 8];
        #pragma unroll
        for (int ni = 0; ni < 4; ++ni)
            bfr[ni] = *(const bf16x8*)&Bs[(wn*64 + ni*16 + (lane & 15)) * 32 + (lane >> 4) * 8];
        #pragma unroll
        for (int mi = 0; mi < 4; ++mi)
            #pragma unroll
            for (int ni = 0; ni < 4; ++ni)
                acc[mi][ni] = __builtin_amdgcn_mfma_f32_16x16x32_bf16(af[mi], bfr[ni], acc[mi][ni], 0, 0, 0);
        __syncthreads();
    }

    const int row0 = bm*128 + wm*64, col0 = bn*128 + wn*64;
    #pragma unroll
    for (int mi = 0; mi < 4; ++mi) {
        #pragma unroll
        for (int ni = 0; ni < 4; ++ni) {
            const int c = col0 + ni*16 + (lane & 15);
            const int r0 = row0 + mi*16 + (lane >> 4)*4;
            const float bv = bias[c];
            float v[4];
            #pragma unroll
            for (int j = 0; j < 4; ++j) v[j] = acc[mi][ni][j] + bv;
            if (EPI == 0) {
                #pragma unroll
                for (int j = 0; j < 4; ++j) ((float*)Cout)[(size_t)(r0+j) * N + c] = v[j];
            } else if (EPI == 1) {
                #pragma unroll
                for (int j = 0; j < 4; ++j)
                    ((float*)Cout)[(size_t)(r0+j) * N + c] = v[j] + res[(size_t)(r0+j) * N + c];
            } else if (EPI == 2) {
                #pragma unroll
                for (int j = 0; j < 4; ++j)
                    ((unsigned short*)Cout)[(size_t)(r0+j) * N + c] = f2bf(gelu_exact(v[j]));
            } else if (EPI == 3) {
                #pragma unroll
                for (int j = 0; j < 4; ++j)
                    ((unsigned short*)Cout)[(size_t)(r0+j) * N + c] = f2bf(v[j]);
            } else {  // EPI == 4: per-head transposed bf16 (V -> VT[bh*HD+d][SEQ])
                const int hh = c >> 7, dd = c & 127;
                const int bb = r0 >> 11, s0 = r0 & 2047;
                ushort4 u;
                u.x = f2bf(v[0]); u.y = f2bf(v[1]); u.z = f2bf(v[2]); u.w = f2bf(v[3]);
                *(ushort4*)((unsigned short*)Cout +
                            ((size_t)((bb*NH + hh)*HD + dd) * SEQ + s0)) = u;
            }
        }
    }
}

// ------------- MFMA flash attention, KV-split partials (bf16, causal) -------
// Equal-split: per q-tile qt (64 rows), 4 pieces; piece ks covers key tiles
// [nt*ks/4, nt*(ks+1)/4), nt = qt+1.  grid (128, NH, BATCH).
// SWAPPED QK^T: sc = mfma(K_frag, Q_frag) -> lane owns one full P row
// (query q = qb + (lane&15)), softmax reduce is lane-local + 2 shfl_xor.
__global__ __launch_bounds__(256) void k_attn_part(const unsigned short* __restrict__ Qb,
                                                   const unsigned short* __restrict__ Kb,
                                                   const unsigned short* __restrict__ VTb,
                                                   float* __restrict__ Opart,
                                                   float* __restrict__ Ml) {
    const int lane = threadIdx.x & 63, w = threadIdx.x >> 6;
    const int g = lane >> 4, c = lane & 15;
    const int h = blockIdx.y, b = blockIdx.z;
    const int qt = blockIdx.x >> 2, ks = blockIdx.x & 3;
    const int nt = qt + 1;
    const int t0 = (nt * ks) >> 2, t1 = (nt * (ks + 1)) >> 2;
    const int qb = qt * 64 + w * 16;
    __shared__ unsigned short p_lds[4][16 * 64];     // per-wave P tile, XOR-swizzled

    // Q fragments: lane holds q row (qb+c), d = dch*32 + g*8 .. +7
    bf16x8 qf[4];
    {
        const unsigned short* qrow = Qb + (size_t)(b*SEQ + qb + c) * EMB + h*HD;
        #pragma unroll
        for (int dch = 0; dch < 4; ++dch)
            qf[dch] = *(const bf16x8*)(qrow + dch*32 + g*8);
    }

    f32x4 o[8];
    #pragma unroll
    for (int ni = 0; ni < 8; ++ni) o[ni] = (f32x4){0.f, 0.f, 0.f, 0.f};
    float m_c = -1e30f, l_c = 0.f;                   // lane-local state, query qb+c

    const int q = qb + c;
    const int qmaxw = qb + 15;                       // wave-uniform causal bound
    const unsigned short* Kbase = Kb  + (size_t)(b*SEQ) * EMB + h*HD;
    const unsigned short* Vbase = VTb + (size_t)((b*NH + h) * HD) * SEQ;
    const float scale = 0.08838834764831845f;        // 1/sqrt(128)
    char* pw = (char*)&p_lds[w][0];

    for (int ti = t0; ti < t1; ++ti) {
        const int tc = ti * 64;
        // ---- QK^T swapped: sc[kt][reg j] = S[key = tc+kt*16+g*4+j][q]
        f32x4 sc[4];
        #pragma unroll
        for (int kt = 0; kt < 4; ++kt) {
            sc[kt] = (f32x4){0.f, 0.f, 0.f, 0.f};
            if (tc + kt*16 <= qmaxw) {               // wave-uniform skip
                const unsigned short* krow = Kbase + (size_t)(tc + kt*16 + c) * EMB;
                #pragma unroll
                for (int dch = 0; dch < 4; ++dch) {
                    bf16x8 kf = *(const bf16x8*)(krow + dch*32 + g*8);
                    sc[kt] = __builtin_amdgcn_mfma_f32_16x16x32_bf16(kf, qf[dch], sc[kt], 0, 0, 0);
                }
            }
        }
        // ---- row max (lane-local over 16 vals + 2 shfl across g-groups)
        float mx = -1e30f;
        #pragma unroll
        for (int kt = 0; kt < 4; ++kt)
            #pragma unroll
            for (int j = 0; j < 4; ++j) {
                const int key = tc + kt*16 + g*4 + j;
                const float s = (key <= q) ? sc[kt][j] * scale : -1e30f;
                mx = fmaxf(mx, s);
            }
        mx = fmaxf(mx, __shfl_xor(mx, 16));
        mx = fmaxf(mx, __shfl_xor(mx, 32));
        // ---- defer-max rescale (T13, THR=8)
        if (!__all(mx <= m_c + 8.f)) {
            const float mn = fmaxf(m_c, mx);
            const float corr = __expf(m_c - mn);
            l_c *= corr;
            m_c = mn;
            #pragma unroll
            for (int j = 0; j < 4; ++j) {
                const float cj = __shfl(corr, g*4 + j);   // corr of query row g*4+j
                #pragma unroll
                for (int ni = 0; ni < 8; ++ni) o[ni][j] *= cj;
            }
        }
        // ---- P = exp(S - m), pack 4 bf16 -> LDS (ds_write_b64), row sum
        float ps = 0.f;
        #pragma unroll
        for (int kt = 0; kt < 4; ++kt) {
            float p[4];
            #pragma unroll
            for (int j = 0; j < 4; ++j) {
                const int key = tc + kt*16 + g*4 + j;
                const float s = (key <= q) ? sc[kt][j] * scale : -1e30f;
                p[j] = __expf(s - m_c);
                ps += p[j];
            }
            uint2 pk;
            pk.x = (unsigned int)f2bf(p[0]) | ((unsigned int)f2bf(p[1]) << 16);
            pk.y = (unsigned int)f2bf(p[2]) | ((unsigned int)f2bf(p[3]) << 16);
            const int byte = (c*128 + kt*32 + g*8) ^ ((c & 7) << 4);
            *(uint2*)(pw + byte) = pk;
        }
        ps += __shfl_xor(ps, 16);
        ps += __shfl_xor(ps, 32);
        l_c += ps;
        asm volatile("s_waitcnt lgkmcnt(0)" ::: "memory");
        __builtin_amdgcn_sched_barrier(0);
        // ---- PV: A = P (row q=c, keys contiguous from swizzled LDS), B = VT
        #pragma unroll
        for (int kc = 0; kc < 2; ++kc) {
            if (tc + kc*32 <= qmaxw) {               // wave-uniform
                const int byte = (c*128 + kc*64 + g*16) ^ ((c & 7) << 4);
                bf16x8 pa = *(const bf16x8*)(pw + byte);
                #pragma unroll
                for (int ni = 0; ni < 8; ++ni) {
                    bf16x8 vf = *(const bf16x8*)(Vbase + (size_t)(ni*16 + c) * SEQ + tc + kc*32 + g*8);
                    o[ni] = __builtin_amdgcn_mfma_f32_16x16x32_bf16(pa, vf, o[ni], 0, 0, 0);
                }
            }
        }
    }

    // ---- epilogue: store unnormalized partial + (m, l)
    const int slot = ((b*NH + h) * 32 + qt) * 4 + ks;
    float* op = Opart + (size_t)slot * (64 * 128);
    #pragma unroll
    for (int ni = 0; ni < 8; ++ni)
        #pragma unroll
        for (int j = 0; j < 4; ++j)
            op[(size_t)(w*16 + g*4 + j) * 128 + ni*16 + c] = o[ni][j];
    if (lane < 16) {
        Ml[(size_t)slot * 128 +      w*16 + lane] = m_c;
        Ml[(size_t)slot * 128 + 64 + w*16 + lane] = l_c;
    }
}

// ------------- combine KV-split partials (4 slots) -> bf16 ctx ---------------
// grid (SEQ/64, NH, BATCH); thread handles one row x 32-col strip
__global__ __launch_bounds__(256) void k_attn_reduce(const float* __restrict__ Opart,
                                                     const float* __restrict__ Ml,
                                                     unsigned short* __restrict__ Ob) {
    const int qt = blockIdx.x, h = blockIdx.y, b = blockIdx.z;
    const int slot0 = ((b*NH + h) * 32 + qt) * 4;
    const int row = threadIdx.x >> 2;
    const int c0 = (threadIdx.x & 3) * 32;
    float M = -1e30f;
    #pragma unroll
    for (int s = 0; s < 4; ++s)
        M = fmaxf(M, Ml[(size_t)(slot0 + s) * 128 + row]);
    float L = 0.f;
    float wgt[4];
    #pragma unroll
    for (int s = 0; s < 4; ++s) {
        wgt[s] = __expf(Ml[(size_t)(slot0 + s) * 128 + row] - M);
        L += Ml[(size_t)(slot0 + s) * 128 + 64 + row] * wgt[s];
    }
    float acc[32];
    #pragma unroll
    for (int k = 0; k < 32; ++k) acc[k] = 0.f;
    #pragma unroll
    for (int s = 0; s < 4; ++s) {
        const float4* op = (const float4*)(Opart + ((size_t)(slot0 + s) * 64 + row) * 128 + c0);
        #pragma unroll
        for (int q4 = 0; q4 < 8; ++q4) {
            float4 v = op[q4];
            acc[q4*4+0] += v.x * wgt[s]; acc[q4*4+1] += v.y * wgt[s];
            acc[q4*4+2] += v.z * wgt[s]; acc[q4*4+3] += v.w * wgt[s];
        }
    }
    const float inv = 1.0f / L;
    unsigned short* orow = Ob + (size_t)(b*SEQ + qt*64 + row) * EMB + h*HD + c0;
    #pragma unroll
    for (int q4 = 0; q4 < 8; ++q4) {
        ushort4 u;
        u.x = f2bf(acc[q4*4+0] * inv); u.y = f2bf(acc[q4*4+1] * inv);
        u.z = f2bf(acc[q4*4+2] * inv); u.w = f2bf(acc[q4*4+3] * inv);
        ((ushort4*)orow)[q4] = u;
    }
}

// ---------------- row LayerNorm over 2048, optional bf16 copy ---------------
__global__ __launch_bounds__(256) void k_ln(const float* __restrict__ X,
                                            const float* __restrict__ g,
                                            const float* __restrict__ be,
                                            float* __restrict__ Of32,
                                            unsigned short* __restrict__ Obf16) {
    const int row = blockIdx.x;
    const float* x = X + (size_t)row * EMB;
    float4 v[2];
    float s = 0.f, ss = 0.f;
    #pragma unroll
    for (int i = 0; i < 2; ++i) {
        v[i] = ((const float4*)x)[threadIdx.x + i*256];
        s  += v[i].x + v[i].y + v[i].z + v[i].w;
        ss += v[i].x*v[i].x + v[i].y*v[i].y + v[i].z*v[i].z + v[i].w*v[i].w;
    }
    #pragma unroll
    for (int o = 32; o; o >>= 1) { s += __shfl_xor(s, o); ss += __shfl_xor(ss, o); }
    __shared__ float red[2][4];
    const int lane = threadIdx.x & 63, wid = threadIdx.x >> 6;
    if (lane == 0) { red[0][wid] = s; red[1][wid] = ss; }
    __syncthreads();
    s  = red[0][0] + red[0][1] + red[0][2] + red[0][3];
    ss = red[1][0] + red[1][1] + red[1][2] + red[1][3];
    const float mu = s * (1.0f / EMB);
    const float var = ss * (1.0f / EMB) - mu * mu;
    const float rs = rsqrtf(var + 1e-5f);
    #pragma unroll
    for (int i = 0; i < 2; ++i) {
        const int c4 = threadIdx.x + i*256;
        float4 gv = ((const float4*)g)[c4];
        float4 bv = ((const float4*)be)[c4];
        float4 y;
        y.x = (v[i].x - mu) * rs * gv.x + bv.x;
        y.y = (v[i].y - mu) * rs * gv.y + bv.y;
        y.z = (v[i].z - mu) * rs * gv.z + bv.z;
        y.w = (v[i].w - mu) * rs * gv.w + bv.w;
        if (Of32)  ((float4*)(Of32 + (size_t)row * EMB))[c4] = y;
        if (Obf16) {
            ushort4 u; u.x = f2bf(y.x); u.y = f2bf(y.y); u.z = f2bf(y.z); u.w = f2bf(y.w);
            ((ushort4*)(Obf16 + (size_t)row * EMB))[c4] = u;
        }
    }
}

extern "C" void kernel_launch(void* const* d_in, const int* in_sizes, int n_in,
                              void* d_out, int out_size, void* d_ws, size_t ws_size,
                              hipStream_t stream) {
    const float* emb = (const float*)d_in[0];
    const float* Wq  = (const float*)d_in[1];  const float* bq  = (const float*)d_in[2];
    const float* Wk  = (const float*)d_in[3];  const float* bk  = (const float*)d_in[4];
    const float* Wv  = (const float*)d_in[5];  const float* bv  = (const float*)d_in[6];
    const float* Wfc = (const float*)d_in[7];  const float* bfc = (const float*)d_in[8];
    const float* g1  = (const float*)d_in[9];  const float* be1 = (const float*)d_in[10];
    const float* W1  = (const float*)d_in[11]; const float* b1  = (const float*)d_in[12];
    const float* W2  = (const float*)d_in[13]; const float* b2  = (const float*)d_in[14];
    const float* g2  = (const float*)d_in[15]; const float* be2 = (const float*)d_in[16];

    // workspace layout (240 MB), lifetime-based reuse.  During attention the
    // regions of ln1B/x1f/ln1f/hB are dead -> partials overlap them.
    char* ws = (char*)d_ws;
    unsigned short* aB   = (unsigned short*)(ws + (size_t)(0  ) * (1u<<20)); // 16MB: emb bf16 -> ctx bf16
    unsigned short* ln1B = (unsigned short*)(ws + (size_t)(16 ) * (1u<<20)); // 16MB (after attn)
    float*          Ml   = (float*)         (ws + (size_t)(16 ) * (1u<<20)); // 2MB during attn (dead after)
    unsigned short* WtB  = (unsigned short*)(ws + (size_t)(32 ) * (1u<<20)); // 32MB transposed weight (serial reuse)
    unsigned short* Qb   = (unsigned short*)(ws + (size_t)(64 ) * (1u<<20)); // 16MB Q bf16
    unsigned short* Kb   = (unsigned short*)(ws + (size_t)(80 ) * (1u<<20)); // 16MB K bf16
    unsigned short* VTb  = (unsigned short*)(ws + (size_t)(96 ) * (1u<<20)); // 16MB V^T bf16 per head
    float*          x1f  = (float*)         (ws + (size_t)(112) * (1u<<20)); // 32MB x1 f32 (after attn)
    float*          Opart= (float*)         (ws + (size_t)(112) * (1u<<20)); // 128MB partials during attn
    float*          ln1f = (float*)         (ws + (size_t)(144) * (1u<<20)); // 32MB ln1 f32 (after attn)
    unsigned short* hB   = (unsigned short*)(ws + (size_t)(176) * (1u<<20)); // 64MB GELU(ffn1) bf16 (after attn)

    const dim3 blk(256);
    const int n4 = MTOK * EMB / 4;

    // embeddings -> bf16
    k_conv<<<dim3(n4 / 256), blk, 0, stream>>>(emb, aB, n4);

    // Q, K projections (bf16 out), V projection (per-head transposed bf16 out)
    k_transconv<<<dim3(EMB/32, EMB/32), blk, 0, stream>>>(Wq, WtB, EMB, EMB);
    k_gemm<3><<<dim3(MTOK/128, EMB/128), blk, 0, stream>>>(aB, WtB, bq, nullptr, Qb, MTOK, EMB, EMB);
    k_transconv<<<dim3(EMB/32, EMB/32), blk, 0, stream>>>(Wk, WtB, EMB, EMB);
    k_gemm<3><<<dim3(MTOK/128, EMB/128), blk, 0, stream>>>(aB, WtB, bk, nullptr, Kb, MTOK, EMB, EMB);
    k_transconv<<<dim3(EMB/32, EMB/32), blk, 0, stream>>>(Wv, WtB, EMB, EMB);
    k_gemm<4><<<dim3(MTOK/128, EMB/128), blk, 0, stream>>>(aB, WtB, bv, nullptr, VTb, MTOK, EMB, EMB);

    // KV-split MFMA flash attention -> partials -> ctx bf16 (overwrites aB)
    k_attn_part<<<dim3(128, NH, BATCH), blk, 0, stream>>>(Qb, Kb, VTb, Opart, Ml);
    k_attn_reduce<<<dim3(SEQ/64, NH, BATCH), blk, 0, stream>>>(Opart, Ml, aB);

    // x1 = ctx@Wfc + bfc + emb -> x1f
    k_transconv<<<dim3(EMB/32, EMB/32), blk, 0, stream>>>(Wfc, WtB, EMB, EMB);
    k_gemm<1><<<dim3(MTOK/128, EMB/128), blk, 0, stream>>>(aB, WtB, bfc, emb, x1f, MTOK, EMB, EMB);

    // LN1 -> f32 (ln1f) + bf16 (ln1B)
    k_ln<<<dim3(MTOK), blk, 0, stream>>>(x1f, g1, be1, ln1f, ln1B);

    // h = gelu(ln1 @ W1 + b1) -> bf16
    k_transconv<<<dim3(4*EMB/32, EMB/32), blk, 0, stream>>>(W1, WtB, EMB, 4*EMB);
    k_gemm<2><<<dim3(MTOK/128, (4*EMB)/128), blk, 0, stream>>>(ln1B, WtB, b1, nullptr, hB, MTOK, 4*EMB, EMB);

    // x2 = h @ W2 + b2 + ln1 -> d_out
    k_transconv<<<dim3(EMB/32, (4*EMB)/32), blk, 0, stream>>>(W2, WtB, 4*EMB, EMB);
    k_gemm<1><<<dim3(MTOK/128, EMB/128), blk, 0, stream>>>(hB, WtB, b2, ln1f, (float*)d_out, MTOK, EMB, 4*EMB);

    // LN2 in-place on d_out
    k_ln<<<dim3(MTOK), blk, 0, stream>>>((const float*)d_out, g2, be2, (float*)d_out, nullptr);
}

// Round 5
// 941.439 us; speedup vs baseline: 1.2638x; 1.2638x over previous
//
#include <hip/hip_runtime.h>
#include <hip/hip_bf16.h>
#include <math.h>

#define EMB  2048
#define NH   16
#define HD   128
#define SEQ  2048
#define BATCH 2
#define MTOK (BATCH*SEQ)   // 4096 tokens

using bf16x8 = __attribute__((ext_vector_type(8))) __bf16;
using f32x4  = __attribute__((ext_vector_type(4))) float;

__device__ __forceinline__ unsigned short f2bf(float x) {
    unsigned int u = __float_as_uint(x);
    u += 0x7fffu + ((u >> 16) & 1u);   // round-to-nearest-even
    return (unsigned short)(u >> 16);
}

__device__ __forceinline__ float gelu_exact(float x) {
    return 0.5f * x * (1.0f + erff(x * 0.70710678118654752f));
}

// ---------------- flat f32 -> bf16 convert (4 elems/thread) ----------------
__global__ __launch_bounds__(256) void k_conv(const float* __restrict__ in,
                                              unsigned short* __restrict__ out, int n4) {
    int i = blockIdx.x * 256 + threadIdx.x;
    if (i >= n4) return;
    float4 v = ((const float4*)in)[i];
    ushort4 o;
    o.x = f2bf(v.x); o.y = f2bf(v.y); o.z = f2bf(v.z); o.w = f2bf(v.w);
    ((ushort4*)out)[i] = o;
}

// ------------- W[K][N] f32 -> Wt[N][K] bf16 (tiled transpose) ---------------
__global__ __launch_bounds__(256) void k_transconv(const float* __restrict__ W,
                                                   unsigned short* __restrict__ Wt,
                                                   int K, int N) {
    __shared__ float t[32][33];
    int tx = threadIdx.x & 31, ty = threadIdx.x >> 5;   // 32 x 8
    int c0 = blockIdx.x * 32, r0 = blockIdx.y * 32;
    #pragma unroll
    for (int i = 0; i < 4; ++i)
        t[ty + i*8][tx] = W[(size_t)(r0 + ty + i*8) * N + c0 + tx];
    __syncthreads();
    #pragma unroll
    for (int i = 0; i < 4; ++i)
        Wt[(size_t)(c0 + ty + i*8) * K + r0 + tx] = f2bf(t[tx][ty + i*8]);
}

// ---------------- bf16 MFMA GEMM: C = A[M,K] @ Bt[N,K]^T + bias -------------
// EPI: 0=f32 out; 1=f32 out + residual; 2=bf16 GELU out; 3=bf16 out;
//      4=bf16 out transposed per-head -> VT[(b*NH+h)*HD + d][SEQ]
template<int EPI>
__global__ __launch_bounds__(256) void k_gemm(const unsigned short* __restrict__ A,
                                              const unsigned short* __restrict__ Bt,
                                              const float* __restrict__ bias,
                                              const float* __restrict__ res,
                                              void* __restrict__ Cout,
                                              int M, int N, int K) {
    __shared__ unsigned short As[128 * 32];
    __shared__ unsigned short Bs[128 * 32];
    const int tid = threadIdx.x;
    const int lane = tid & 63, wid = tid >> 6;
    const int wm = wid >> 1, wn = wid & 1;            // 2x2 waves, 64x64 each
    const int bm = blockIdx.x, bn = blockIdx.y;
    f32x4 acc[4][4] = {};
    const int srow = wid * 16 + (lane >> 2);          // staging row within 64-row half
    const int scol = (lane & 3) * 8;                  // staging col (8 bf16 = 16B)
    const unsigned short* Ab = A  + (size_t)bm * 128 * K;
    const unsigned short* Bb = Bt + (size_t)bn * 128 * K;

    for (int kt = 0; kt < K; kt += 32) {
        #pragma unroll
        for (int i = 0; i < 2; ++i) {
            const unsigned short* ga = Ab + (size_t)(i*64 + srow) * K + kt + scol;
            const unsigned short* gb = Bb + (size_t)(i*64 + srow) * K + kt + scol;
            __builtin_amdgcn_global_load_lds(
                (const __attribute__((address_space(1))) void*)ga,
                (__attribute__((address_space(3))) void*)&As[(i*64 + wid*16) * 32], 16, 0, 0);
            __builtin_amdgcn_global_load_lds(
                (const __attribute__((address_space(1))) void*)gb,
                (__attribute__((address_space(3))) void*)&Bs[(i*64 + wid*16) * 32], 16, 0, 0);
        }
        __syncthreads();

        bf16x8 af[4], bfr[4];
        #pragma unroll
        for (int mi = 0; mi < 4; ++mi)
            af[mi] = *(const bf16x8*)&As[(wm*64 + mi*16 + (lane & 15)) * 32 + (lane >> 4) * 8];
        #pragma unroll
        for (int ni = 0; ni < 4; ++ni)
            bfr[ni] = *(const bf16x8*)&Bs[(wn*64 + ni*16 + (lane & 15)) * 32 + (lane >> 4) * 8];
        #pragma unroll
        for (int mi = 0; mi < 4; ++mi)
            #pragma unroll
            for (int ni = 0; ni < 4; ++ni)
                acc[mi][ni] = __builtin_amdgcn_mfma_f32_16x16x32_bf16(af[mi], bfr[ni], acc[mi][ni], 0, 0, 0);
        __syncthreads();
    }

    const int row0 = bm*128 + wm*64, col0 = bn*128 + wn*64;
    #pragma unroll
    for (int mi = 0; mi < 4; ++mi) {
        #pragma unroll
        for (int ni = 0; ni < 4; ++ni) {
            const int c = col0 + ni*16 + (lane & 15);
            const int r0 = row0 + mi*16 + (lane >> 4)*4;
            const float bv = bias[c];
            float v[4];
            #pragma unroll
            for (int j = 0; j < 4; ++j) v[j] = acc[mi][ni][j] + bv;
            if (EPI == 0) {
                #pragma unroll
                for (int j = 0; j < 4; ++j) ((float*)Cout)[(size_t)(r0+j) * N + c] = v[j];
            } else if (EPI == 1) {
                #pragma unroll
                for (int j = 0; j < 4; ++j)
                    ((float*)Cout)[(size_t)(r0+j) * N + c] = v[j] + res[(size_t)(r0+j) * N + c];
            } else if (EPI == 2) {
                #pragma unroll
                for (int j = 0; j < 4; ++j)
                    ((unsigned short*)Cout)[(size_t)(r0+j) * N + c] = f2bf(gelu_exact(v[j]));
            } else if (EPI == 3) {
                #pragma unroll
                for (int j = 0; j < 4; ++j)
                    ((unsigned short*)Cout)[(size_t)(r0+j) * N + c] = f2bf(v[j]);
            } else {  // EPI == 4: per-head transposed bf16 (V -> VT[bh*HD+d][SEQ])
                const int hh = c >> 7, dd = c & 127;
                const int bb = r0 >> 11, s0 = r0 & 2047;
                ushort4 u;
                u.x = f2bf(v[0]); u.y = f2bf(v[1]); u.z = f2bf(v[2]); u.w = f2bf(v[3]);
                *(ushort4*)((unsigned short*)Cout +
                            ((size_t)((bb*NH + hh)*HD + dd) * SEQ + s0)) = u;
            }
        }
    }
}

// ------------- MFMA flash attention, KV-split partials (bf16, causal) -------
// Equal-split: per q-tile qt (64 rows), 4 pieces; piece ks covers key tiles
// [nt*ks/4, nt*(ks+1)/4), nt = qt+1.  1D grid 4096, XCD-swizzled decode.
// K and V^T tiles staged cooperatively into LDS (global_load_lds width 16,
// 16B-chunk XOR swizzle pre-applied on the GLOBAL source, applied again on
// the LDS read -- both-sides involution).  SWAPPED QK^T (lane owns P row).
__global__ __launch_bounds__(256, 4) void k_attn_part(const unsigned short* __restrict__ Qb,
                                                      const unsigned short* __restrict__ Kb,
                                                      const unsigned short* __restrict__ VTb,
                                                      float* __restrict__ Opart,
                                                      float* __restrict__ Ml) {
    const int tid = threadIdx.x;
    const int lane = tid & 63, w = tid >> 6;
    const int g = lane >> 4, c = lane & 15;
    // XCD-aware decode: 512 consecutive swz (= 4 (b,h) pairs, ~4MB K/V) per XCD
    const int bid = blockIdx.x;
    const int swz = (bid & 7) * 512 + (bid >> 3);
    const int bh = swz >> 7;
    const int b = bh >> 4, h = bh & 15;
    const int rr = swz & 127;
    const int qt = rr >> 2, ks = rr & 3;
    const int nt = qt + 1;
    const int t0 = (nt * ks) >> 2, t1 = (nt * (ks + 1)) >> 2;
    const int qb = qt * 64 + w * 16;

    __shared__ unsigned short Ks[64 * 128];      // [key][d], 256B rows, chunk-swizzled
    __shared__ unsigned short Vs[128 * 64];      // [d][key], 128B rows, chunk-swizzled
    __shared__ unsigned short p_lds[4][16 * 64]; // per-wave P tile, XOR-swizzled

    // Q fragments: lane holds q row (qb+c), d = dch*32 + g*8 .. +7
    bf16x8 qf[4];
    {
        const unsigned short* qrow = Qb + (size_t)(b*SEQ + qb + c) * EMB + h*HD;
        #pragma unroll
        for (int dch = 0; dch < 4; ++dch)
            qf[dch] = *(const bf16x8*)(qrow + dch*32 + g*8);
    }

    f32x4 o[8];
    #pragma unroll
    for (int ni = 0; ni < 8; ++ni) o[ni] = (f32x4){0.f, 0.f, 0.f, 0.f};
    float m_c = -1e30f, l_c = 0.f;                   // lane-local state, query qb+c

    const int q = qb + c;
    const int qmaxw = qb + 15;                       // wave-uniform causal bound
    const unsigned short* Kbase = Kb  + (size_t)(b*SEQ) * EMB + h*HD;
    const unsigned short* Vbase = VTb + (size_t)((b*NH + h) * HD) * SEQ;
    const float scale = 0.08838834764831845f;        // 1/sqrt(128)
    char* pw = (char*)&p_lds[w][0];

    for (int ti = t0; ti < t1; ++ti) {
        const int tc = ti * 64;
        // ---- cooperative stage: K 64x128 + V^T 128x64 (1024 chunks each)
        // LDS dest is wave-uniform base (+ implicit lane*16B); global src is
        // per-lane with the inverse (== same) chunk XOR swizzle applied.
        #pragma unroll
        for (int it = 0; it < 4; ++it) {
            const int cl = it * 256 + tid;           // this lane's chunk index
            const unsigned short* gk = Kbase + (size_t)(tc + (cl >> 4)) * EMB
                                     + (((cl & 15) ^ ((cl >> 4) & 7)) * 8);
            __builtin_amdgcn_global_load_lds(
                (const __attribute__((address_space(1))) void*)gk,
                (__attribute__((address_space(3))) void*)&Ks[(it*256 + w*64) * 8], 16, 0, 0);
            const unsigned short* gv = Vbase + (size_t)(cl >> 3) * SEQ + tc
                                     + (((cl & 7) ^ ((cl >> 3) & 7)) * 8);
            __builtin_amdgcn_global_load_lds(
                (const __attribute__((address_space(1))) void*)gv,
                (__attribute__((address_space(3))) void*)&Vs[(it*256 + w*64) * 8], 16, 0, 0);
        }
        __syncthreads();                              // vmcnt drained by compiler

        // ---- QK^T swapped from LDS: sc[kt][j] = S[key = tc+kt*16+g*4+j][q]
        f32x4 sc[4];
        #pragma unroll
        for (int kt = 0; kt < 4; ++kt) {
            sc[kt] = (f32x4){0.f, 0.f, 0.f, 0.f};
            if (tc + kt*16 <= qmaxw) {               // wave-uniform skip
                #pragma unroll
                for (int dch = 0; dch < 4; ++dch) {
                    bf16x8 kf = *(const bf16x8*)&Ks[(kt*16 + c)*128 + (((dch*4 + g) ^ (c & 7)) * 8)];
                    sc[kt] = __builtin_amdgcn_mfma_f32_16x16x32_bf16(kf, qf[dch], sc[kt], 0, 0, 0);
                }
            }
        }
        // ---- row max (lane-local over 16 vals + 2 shfl across g-groups)
        float mx = -1e30f;
        #pragma unroll
        for (int kt = 0; kt < 4; ++kt)
            #pragma unroll
            for (int j = 0; j < 4; ++j) {
                const int key = tc + kt*16 + g*4 + j;
                const float s = (key <= q) ? sc[kt][j] * scale : -1e30f;
                mx = fmaxf(mx, s);
            }
        mx = fmaxf(mx, __shfl_xor(mx, 16));
        mx = fmaxf(mx, __shfl_xor(mx, 32));
        // ---- defer-max rescale (T13, THR=8)
        if (!__all(mx <= m_c + 8.f)) {
            const float mn = fmaxf(m_c, mx);
            const float corr = __expf(m_c - mn);
            l_c *= corr;
            m_c = mn;
            #pragma unroll
            for (int j = 0; j < 4; ++j) {
                const float cj = __shfl(corr, g*4 + j);   // corr of query row g*4+j
                #pragma unroll
                for (int ni = 0; ni < 8; ++ni) o[ni][j] *= cj;
            }
        }
        // ---- P = exp(S - m), pack 4 bf16 -> LDS (8B writes), row sum
        float ps = 0.f;
        #pragma unroll
        for (int kt = 0; kt < 4; ++kt) {
            float p[4];
            #pragma unroll
            for (int j = 0; j < 4; ++j) {
                const int key = tc + kt*16 + g*4 + j;
                const float s = (key <= q) ? sc[kt][j] * scale : -1e30f;
                p[j] = __expf(s - m_c);
                ps += p[j];
            }
            uint2 pk;
            pk.x = (unsigned int)f2bf(p[0]) | ((unsigned int)f2bf(p[1]) << 16);
            pk.y = (unsigned int)f2bf(p[2]) | ((unsigned int)f2bf(p[3]) << 16);
            const int byte = (c*128 + kt*32 + g*8) ^ ((c & 7) << 4);
            *(uint2*)(pw + byte) = pk;
        }
        ps += __shfl_xor(ps, 16);
        ps += __shfl_xor(ps, 32);
        l_c += ps;
        asm volatile("s_waitcnt lgkmcnt(0)" ::: "memory");
        __builtin_amdgcn_sched_barrier(0);
        // ---- PV: A = P (row q=c from swizzled LDS), B = V^T from LDS
        #pragma unroll
        for (int kc = 0; kc < 2; ++kc) {
            if (tc + kc*32 <= qmaxw) {               // wave-uniform
                const int byte = (c*128 + kc*64 + g*16) ^ ((c & 7) << 4);
                bf16x8 pa = *(const bf16x8*)(pw + byte);
                #pragma unroll
                for (int ni = 0; ni < 8; ++ni) {
                    bf16x8 vf = *(const bf16x8*)&Vs[(ni*16 + c)*64 + (((kc*4 + g) ^ (c & 7)) * 8)];
                    o[ni] = __builtin_amdgcn_mfma_f32_16x16x32_bf16(pa, vf, o[ni], 0, 0, 0);
                }
            }
        }
        __syncthreads();                              // before next stage overwrites
    }

    // ---- epilogue: store unnormalized partial + (m, l)
    const int slot = ((b*NH + h) * 32 + qt) * 4 + ks;
    float* op = Opart + (size_t)slot * (64 * 128);
    #pragma unroll
    for (int ni = 0; ni < 8; ++ni)
        #pragma unroll
        for (int j = 0; j < 4; ++j)
            op[(size_t)(w*16 + g*4 + j) * 128 + ni*16 + c] = o[ni][j];
    if (lane < 16) {
        Ml[(size_t)slot * 128 +      w*16 + lane] = m_c;
        Ml[(size_t)slot * 128 + 64 + w*16 + lane] = l_c;
    }
}

// ------------- combine KV-split partials (4 slots) -> bf16 ctx ---------------
// grid (SEQ/64, NH, BATCH); thread handles one row x 32-col strip
__global__ __launch_bounds__(256) void k_attn_reduce(const float* __restrict__ Opart,
                                                     const float* __restrict__ Ml,
                                                     unsigned short* __restrict__ Ob) {
    const int qt = blockIdx.x, h = blockIdx.y, b = blockIdx.z;
    const int slot0 = ((b*NH + h) * 32 + qt) * 4;
    const int row = threadIdx.x >> 2;
    const int c0 = (threadIdx.x & 3) * 32;
    float M = -1e30f;
    #pragma unroll
    for (int s = 0; s < 4; ++s)
        M = fmaxf(M, Ml[(size_t)(slot0 + s) * 128 + row]);
    float L = 0.f;
    float wgt[4];
    #pragma unroll
    for (int s = 0; s < 4; ++s) {
        wgt[s] = __expf(Ml[(size_t)(slot0 + s) * 128 + row] - M);
        L += Ml[(size_t)(slot0 + s) * 128 + 64 + row] * wgt[s];
    }
    float acc[32];
    #pragma unroll
    for (int k = 0; k < 32; ++k) acc[k] = 0.f;
    #pragma unroll
    for (int s = 0; s < 4; ++s) {
        const float4* op = (const float4*)(Opart + ((size_t)(slot0 + s) * 64 + row) * 128 + c0);
        #pragma unroll
        for (int q4 = 0; q4 < 8; ++q4) {
            float4 v = op[q4];
            acc[q4*4+0] += v.x * wgt[s]; acc[q4*4+1] += v.y * wgt[s];
            acc[q4*4+2] += v.z * wgt[s]; acc[q4*4+3] += v.w * wgt[s];
        }
    }
    const float inv = 1.0f / L;
    unsigned short* orow = Ob + (size_t)(b*SEQ + qt*64 + row) * EMB + h*HD + c0;
    #pragma unroll
    for (int q4 = 0; q4 < 8; ++q4) {
        ushort4 u;
        u.x = f2bf(acc[q4*4+0] * inv); u.y = f2bf(acc[q4*4+1] * inv);
        u.z = f2bf(acc[q4*4+2] * inv); u.w = f2bf(acc[q4*4+3] * inv);
        ((ushort4*)orow)[q4] = u;
    }
}

// ---------------- row LayerNorm over 2048, optional bf16 copy ---------------
__global__ __launch_bounds__(256) void k_ln(const float* __restrict__ X,
                                            const float* __restrict__ g,
                                            const float* __restrict__ be,
                                            float* __restrict__ Of32,
                                            unsigned short* __restrict__ Obf16) {
    const int row = blockIdx.x;
    const float* x = X + (size_t)row * EMB;
    float4 v[2];
    float s = 0.f, ss = 0.f;
    #pragma unroll
    for (int i = 0; i < 2; ++i) {
        v[i] = ((const float4*)x)[threadIdx.x + i*256];
        s  += v[i].x + v[i].y + v[i].z + v[i].w;
        ss += v[i].x*v[i].x + v[i].y*v[i].y + v[i].z*v[i].z + v[i].w*v[i].w;
    }
    #pragma unroll
    for (int o = 32; o; o >>= 1) { s += __shfl_xor(s, o); ss += __shfl_xor(ss, o); }
    __shared__ float red[2][4];
    const int lane = threadIdx.x & 63, wid = threadIdx.x >> 6;
    if (lane == 0) { red[0][wid] = s; red[1][wid] = ss; }
    __syncthreads();
    s  = red[0][0] + red[0][1] + red[0][2] + red[0][3];
    ss = red[1][0] + red[1][1] + red[1][2] + red[1][3];
    const float mu = s * (1.0f / EMB);
    const float var = ss * (1.0f / EMB) - mu * mu;
    const float rs = rsqrtf(var + 1e-5f);
    #pragma unroll
    for (int i = 0; i < 2; ++i) {
        const int c4 = threadIdx.x + i*256;
        float4 gv = ((const float4*)g)[c4];
        float4 bv = ((const float4*)be)[c4];
        float4 y;
        y.x = (v[i].x - mu) * rs * gv.x + bv.x;
        y.y = (v[i].y - mu) * rs * gv.y + bv.y;
        y.z = (v[i].z - mu) * rs * gv.z + bv.z;
        y.w = (v[i].w - mu) * rs * gv.w + bv.w;
        if (Of32)  ((float4*)(Of32 + (size_t)row * EMB))[c4] = y;
        if (Obf16) {
            ushort4 u; u.x = f2bf(y.x); u.y = f2bf(y.y); u.z = f2bf(y.z); u.w = f2bf(y.w);
            ((ushort4*)(Obf16 + (size_t)row * EMB))[c4] = u;
        }
    }
}

extern "C" void kernel_launch(void* const* d_in, const int* in_sizes, int n_in,
                              void* d_out, int out_size, void* d_ws, size_t ws_size,
                              hipStream_t stream) {
    const float* emb = (const float*)d_in[0];
    const float* Wq  = (const float*)d_in[1];  const float* bq  = (const float*)d_in[2];
    const float* Wk  = (const float*)d_in[3];  const float* bk  = (const float*)d_in[4];
    const float* Wv  = (const float*)d_in[5];  const float* bv  = (const float*)d_in[6];
    const float* Wfc = (const float*)d_in[7];  const float* bfc = (const float*)d_in[8];
    const float* g1  = (const float*)d_in[9];  const float* be1 = (const float*)d_in[10];
    const float* W1  = (const float*)d_in[11]; const float* b1  = (const float*)d_in[12];
    const float* W2  = (const float*)d_in[13]; const float* b2  = (const float*)d_in[14];
    const float* g2  = (const float*)d_in[15]; const float* be2 = (const float*)d_in[16];

    // workspace layout (240 MB), lifetime-based reuse.  During attention the
    // regions of ln1B/x1f/ln1f/hB are dead -> partials overlap them.
    char* ws = (char*)d_ws;
    unsigned short* aB   = (unsigned short*)(ws + (size_t)(0  ) * (1u<<20)); // 16MB: emb bf16 -> ctx bf16
    unsigned short* ln1B = (unsigned short*)(ws + (size_t)(16 ) * (1u<<20)); // 16MB (after attn)
    float*          Ml   = (float*)         (ws + (size_t)(16 ) * (1u<<20)); // 2MB during attn (dead after)
    unsigned short* WtB  = (unsigned short*)(ws + (size_t)(32 ) * (1u<<20)); // 32MB transposed weight (serial reuse)
    unsigned short* Qb   = (unsigned short*)(ws + (size_t)(64 ) * (1u<<20)); // 16MB Q bf16
    unsigned short* Kb   = (unsigned short*)(ws + (size_t)(80 ) * (1u<<20)); // 16MB K bf16
    unsigned short* VTb  = (unsigned short*)(ws + (size_t)(96 ) * (1u<<20)); // 16MB V^T bf16 per head
    float*          x1f  = (float*)         (ws + (size_t)(112) * (1u<<20)); // 32MB x1 f32 (after attn)
    float*          Opart= (float*)         (ws + (size_t)(112) * (1u<<20)); // 128MB partials during attn
    float*          ln1f = (float*)         (ws + (size_t)(144) * (1u<<20)); // 32MB ln1 f32 (after attn)
    unsigned short* hB   = (unsigned short*)(ws + (size_t)(176) * (1u<<20)); // 64MB GELU(ffn1) bf16 (after attn)

    const dim3 blk(256);
    const int n4 = MTOK * EMB / 4;

    // embeddings -> bf16
    k_conv<<<dim3(n4 / 256), blk, 0, stream>>>(emb, aB, n4);

    // Q, K projections (bf16 out), V projection (per-head transposed bf16 out)
    k_transconv<<<dim3(EMB/32, EMB/32), blk, 0, stream>>>(Wq, WtB, EMB, EMB);
    k_gemm<3><<<dim3(MTOK/128, EMB/128), blk, 0, stream>>>(aB, WtB, bq, nullptr, Qb, MTOK, EMB, EMB);
    k_transconv<<<dim3(EMB/32, EMB/32), blk, 0, stream>>>(Wk, WtB, EMB, EMB);
    k_gemm<3><<<dim3(MTOK/128, EMB/128), blk, 0, stream>>>(aB, WtB, bk, nullptr, Kb, MTOK, EMB, EMB);
    k_transconv<<<dim3(EMB/32, EMB/32), blk, 0, stream>>>(Wv, WtB, EMB, EMB);
    k_gemm<4><<<dim3(MTOK/128, EMB/128), blk, 0, stream>>>(aB, WtB, bv, nullptr, VTb, MTOK, EMB, EMB);

    // KV-split MFMA flash attention -> partials -> ctx bf16 (overwrites aB)
    k_attn_part<<<dim3(4096), blk, 0, stream>>>(Qb, Kb, VTb, Opart, Ml);
    k_attn_reduce<<<dim3(SEQ/64, NH, BATCH), blk, 0, stream>>>(Opart, Ml, aB);

    // x1 = ctx@Wfc + bfc + emb -> x1f
    k_transconv<<<dim3(EMB/32, EMB/32), blk, 0, stream>>>(Wfc, WtB, EMB, EMB);
    k_gemm<1><<<dim3(MTOK/128, EMB/128), blk, 0, stream>>>(aB, WtB, bfc, emb, x1f, MTOK, EMB, EMB);

    // LN1 -> f32 (ln1f) + bf16 (ln1B)
    k_ln<<<dim3(MTOK), blk, 0, stream>>>(x1f, g1, be1, ln1f, ln1B);

    // h = gelu(ln1 @ W1 + b1) -> bf16
    k_transconv<<<dim3(4*EMB/32, EMB/32), blk, 0, stream>>>(W1, WtB, EMB, 4*EMB);
    k_gemm<2><<<dim3(MTOK/128, (4*EMB)/128), blk, 0, stream>>>(ln1B, WtB, b1, nullptr, hB, MTOK, 4*EMB, EMB);

    // x2 = h @ W2 + b2 + ln1 -> d_out
    k_transconv<<<dim3(EMB/32, (4*EMB)/32), blk, 0, stream>>>(W2, WtB, 4*EMB, EMB);
    k_gemm<1><<<dim3(MTOK/128, EMB/128), blk, 0, stream>>>(hB, WtB, b2, ln1f, (float*)d_out, MTOK, EMB, 4*EMB);

    // LN2 in-place on d_out
    k_ln<<<dim3(MTOK), blk, 0, stream>>>((const float*)d_out, g2, be2, (float*)d_out, nullptr);
}

// Round 6
// 867.255 us; speedup vs baseline: 1.3719x; 1.0855x over previous
//
#include <hip/hip_runtime.h>
#include <hip/hip_bf16.h>
#include <math.h>

#define EMB  2048
#define NH   16
#define HD   128
#define SEQ  2048
#define BATCH 2
#define MTOK (BATCH*SEQ)   // 4096 tokens

using bf16x8 = __attribute__((ext_vector_type(8))) __bf16;
using f32x4  = __attribute__((ext_vector_type(4))) float;

__device__ __forceinline__ unsigned short f2bf(float x) {
    unsigned int u = __float_as_uint(x);
    u += 0x7fffu + ((u >> 16) & 1u);   // round-to-nearest-even
    return (unsigned short)(u >> 16);
}

__device__ __forceinline__ float gelu_exact(float x) {
    return 0.5f * x * (1.0f + erff(x * 0.70710678118654752f));
}

// ---------------- flat f32 -> bf16 convert (4 elems/thread) ----------------
__global__ __launch_bounds__(256) void k_conv(const float* __restrict__ in,
                                              unsigned short* __restrict__ out, int n4) {
    int i = blockIdx.x * 256 + threadIdx.x;
    if (i >= n4) return;
    float4 v = ((const float4*)in)[i];
    ushort4 o;
    o.x = f2bf(v.x); o.y = f2bf(v.y); o.z = f2bf(v.z); o.w = f2bf(v.w);
    ((ushort4*)out)[i] = o;
}

// ------------- W[K][N] f32 -> Wt[N][K] bf16 (tiled transpose) ---------------
__global__ __launch_bounds__(256) void k_transconv(const float* __restrict__ W,
                                                   unsigned short* __restrict__ Wt,
                                                   int K, int N) {
    __shared__ float t[32][33];
    int tx = threadIdx.x & 31, ty = threadIdx.x >> 5;   // 32 x 8
    int c0 = blockIdx.x * 32, r0 = blockIdx.y * 32;
    #pragma unroll
    for (int i = 0; i < 4; ++i)
        t[ty + i*8][tx] = W[(size_t)(r0 + ty + i*8) * N + c0 + tx];
    __syncthreads();
    #pragma unroll
    for (int i = 0; i < 4; ++i)
        Wt[(size_t)(c0 + ty + i*8) * K + r0 + tx] = f2bf(t[tx][ty + i*8]);
}

// ------------- 256xBN deep-pipelined bf16 MFMA GEMM -------------------------
// C = A[M,K] @ Bt[N,K]^T + bias.  512 threads = 8 waves (2 wm x 4 wn); wave
// output 128 x (BN/4).  BK=64, 2 LDS K-tile buffers, prefetch K-tile t+2
// issued after compute-end barrier of tile t; counted vmcnt (never 0 in
// steady state) keeps loads in flight across barriers (T3/T4).
// LDS tiles are 16B-chunk XOR-swizzled (chunk ^= row&7) with the inverse
// swizzle pre-applied on the GLOBAL source (both-sides involution, rule #21).
// EPI: 0=f32; 1=f32+res; 2=bf16 gelu; 3=bf16; 4=bf16 per-head V^T
template<int BN, int EPI>
__global__ __launch_bounds__(512, 1) void k_gemm2(const unsigned short* __restrict__ A,
                                                  const unsigned short* __restrict__ Bt,
                                                  const float* __restrict__ bias,
                                                  const float* __restrict__ res,
                                                  void* __restrict__ Cout,
                                                  int M, int N, int K) {
    constexpr int WN  = BN / 4;          // wave N extent (64 or 32)
    constexpr int NF  = WN / 16;         // N frags per wave (4 or 2)
    constexpr int BIT = (BN * 8) / 512;  // B staging iterations (4 or 2)
    __shared__ unsigned short As[2][256 * 64];
    __shared__ unsigned short Bs[2][BN * 64];
    const int tid = threadIdx.x, lane = tid & 63, wid = tid >> 6;
    const int wm = wid >> 2, wn = wid & 3;
    // XCD-chunked rasterization: contiguous swz per XCD, bm-fast
    const int nmt = M >> 8, nnt = N / BN, nblk = nmt * nnt;
    const int cpx = nblk >> 3;
    const int swz = (blockIdx.x & 7) * cpx + (blockIdx.x >> 3);
    const int bm = swz % nmt, bn = swz / nmt;
    const unsigned short* Ab = A  + (size_t)bm * 256 * K;
    const unsigned short* Bb = Bt + (size_t)bn * BN  * K;

    auto STAGE = [&](int ti, int bbuf) {
        const int kt = ti * 64;
        #pragma unroll
        for (int it = 0; it < 4; ++it) {
            const int slot = it * 512 + tid;
            const int r = slot >> 3, cs = slot & 7;
            const unsigned short* g = Ab + (size_t)r * K + kt + ((cs ^ (r & 7)) * 8);
            __builtin_amdgcn_global_load_lds(
                (const __attribute__((address_space(1))) void*)g,
                (__attribute__((address_space(3))) void*)&As[bbuf][(it*512 + wid*64) * 8], 16, 0, 0);
        }
        #pragma unroll
        for (int it = 0; it < BIT; ++it) {
            const int slot = it * 512 + tid;
            const int r = slot >> 3, cs = slot & 7;
            const unsigned short* g = Bb + (size_t)r * K + kt + ((cs ^ (r & 7)) * 8);
            __builtin_amdgcn_global_load_lds(
                (const __attribute__((address_space(1))) void*)g,
                (__attribute__((address_space(3))) void*)&Bs[bbuf][(it*512 + wid*64) * 8], 16, 0, 0);
        }
    };

    f32x4 acc[8][NF] = {};
    const int NT = K >> 6;
    STAGE(0, 0);
    STAGE(1, 1);

    for (int t = 0; t < NT; ++t) {
        const int bb = t & 1;
        if (t == NT - 1)      asm volatile("s_waitcnt vmcnt(0)" ::: "memory");
        else if (BN == 256)   asm volatile("s_waitcnt vmcnt(8)" ::: "memory");
        else                  asm volatile("s_waitcnt vmcnt(6)" ::: "memory");
        __builtin_amdgcn_s_barrier();
        __builtin_amdgcn_sched_barrier(0);

        #pragma unroll
        for (int kh = 0; kh < 2; ++kh) {
            bf16x8 af[8];
            #pragma unroll
            for (int mi = 0; mi < 8; ++mi) {
                const int r = wm*128 + mi*16 + (lane & 15);
                af[mi] = *(const bf16x8*)&As[bb][r*64 + (((kh*4 + (lane >> 4)) ^ (lane & 7)) * 8)];
            }
            bf16x8 bfr[NF];
            #pragma unroll
            for (int ni = 0; ni < NF; ++ni) {
                const int r = wn*WN + ni*16 + (lane & 15);
                bfr[ni] = *(const bf16x8*)&Bs[bb][r*64 + (((kh*4 + (lane >> 4)) ^ (lane & 7)) * 8)];
            }
            #pragma unroll
            for (int mi = 0; mi < 8; ++mi)
                #pragma unroll
                for (int ni = 0; ni < NF; ++ni)
                    acc[mi][ni] = __builtin_amdgcn_mfma_f32_16x16x32_bf16(af[mi], bfr[ni], acc[mi][ni], 0, 0, 0);
        }

        __builtin_amdgcn_sched_barrier(0);
        __builtin_amdgcn_s_barrier();
        __builtin_amdgcn_sched_barrier(0);
        if (t + 2 < NT) STAGE(t + 2, bb);
    }

    const int row0b = bm*256 + wm*128, col0 = bn*BN + wn*WN;
    #pragma unroll
    for (int mi = 0; mi < 8; ++mi) {
        #pragma unroll
        for (int ni = 0; ni < NF; ++ni) {
            const int c = col0 + ni*16 + (lane & 15);
            const int r0 = row0b + mi*16 + (lane >> 4) * 4;
            const float bv = bias[c];
            float v[4];
            #pragma unroll
            for (int j = 0; j < 4; ++j) v[j] = acc[mi][ni][j] + bv;
            if (EPI == 0) {
                #pragma unroll
                for (int j = 0; j < 4; ++j) ((float*)Cout)[(size_t)(r0+j) * N + c] = v[j];
            } else if (EPI == 1) {
                #pragma unroll
                for (int j = 0; j < 4; ++j)
                    ((float*)Cout)[(size_t)(r0+j) * N + c] = v[j] + res[(size_t)(r0+j) * N + c];
            } else if (EPI == 2) {
                #pragma unroll
                for (int j = 0; j < 4; ++j)
                    ((unsigned short*)Cout)[(size_t)(r0+j) * N + c] = f2bf(gelu_exact(v[j]));
            } else if (EPI == 3) {
                #pragma unroll
                for (int j = 0; j < 4; ++j)
                    ((unsigned short*)Cout)[(size_t)(r0+j) * N + c] = f2bf(v[j]);
            } else {  // EPI == 4: per-head transposed bf16 (V -> VT[bh*HD+d][SEQ])
                const int hh = c >> 7, dd = c & 127;
                const int bb2 = r0 >> 11, s0 = r0 & 2047;
                ushort4 u;
                u.x = f2bf(v[0]); u.y = f2bf(v[1]); u.z = f2bf(v[2]); u.w = f2bf(v[3]);
                *(ushort4*)((unsigned short*)Cout +
                            ((size_t)((bb2*NH + hh)*HD + dd) * SEQ + s0)) = u;
            }
        }
    }
}

// ------------- MFMA flash attention, KV-split partials (bf16, causal) -------
// Equal-split: per q-tile qt (64 rows), 4 pieces; piece ks covers key tiles
// [nt*ks/4, nt*(ks+1)/4), nt = qt+1.  1D grid 4096, XCD-swizzled decode.
// K and V^T tiles staged cooperatively into LDS (global_load_lds width 16,
// 16B-chunk XOR swizzle pre-applied on the GLOBAL source, applied again on
// the LDS read -- both-sides involution).  SWAPPED QK^T (lane owns P row).
__global__ __launch_bounds__(256, 4) void k_attn_part(const unsigned short* __restrict__ Qb,
                                                      const unsigned short* __restrict__ Kb,
                                                      const unsigned short* __restrict__ VTb,
                                                      float* __restrict__ Opart,
                                                      float* __restrict__ Ml) {
    const int tid = threadIdx.x;
    const int lane = tid & 63, w = tid >> 6;
    const int g = lane >> 4, c = lane & 15;
    // XCD-aware decode: 512 consecutive swz (= 4 (b,h) pairs, ~4MB K/V) per XCD
    const int bid = blockIdx.x;
    const int swz = (bid & 7) * 512 + (bid >> 3);
    const int bh = swz >> 7;
    const int b = bh >> 4, h = bh & 15;
    const int rr = swz & 127;
    const int qt = rr >> 2, ks = rr & 3;
    const int nt = qt + 1;
    const int t0 = (nt * ks) >> 2, t1 = (nt * (ks + 1)) >> 2;
    const int qb = qt * 64 + w * 16;

    __shared__ unsigned short Ks[64 * 128];      // [key][d], 256B rows, chunk-swizzled
    __shared__ unsigned short Vs[128 * 64];      // [d][key], 128B rows, chunk-swizzled
    __shared__ unsigned short p_lds[4][16 * 64]; // per-wave P tile, XOR-swizzled

    // Q fragments: lane holds q row (qb+c), d = dch*32 + g*8 .. +7
    bf16x8 qf[4];
    {
        const unsigned short* qrow = Qb + (size_t)(b*SEQ + qb + c) * EMB + h*HD;
        #pragma unroll
        for (int dch = 0; dch < 4; ++dch)
            qf[dch] = *(const bf16x8*)(qrow + dch*32 + g*8);
    }

    f32x4 o[8];
    #pragma unroll
    for (int ni = 0; ni < 8; ++ni) o[ni] = (f32x4){0.f, 0.f, 0.f, 0.f};
    float m_c = -1e30f, l_c = 0.f;                   // lane-local state, query qb+c

    const int q = qb + c;
    const int qmaxw = qb + 15;                       // wave-uniform causal bound
    const unsigned short* Kbase = Kb  + (size_t)(b*SEQ) * EMB + h*HD;
    const unsigned short* Vbase = VTb + (size_t)((b*NH + h) * HD) * SEQ;
    const float scale = 0.08838834764831845f;        // 1/sqrt(128)
    char* pw = (char*)&p_lds[w][0];

    for (int ti = t0; ti < t1; ++ti) {
        const int tc = ti * 64;
        // ---- cooperative stage: K 64x128 + V^T 128x64 (1024 chunks each)
        #pragma unroll
        for (int it = 0; it < 4; ++it) {
            const int cl = it * 256 + tid;           // this lane's chunk index
            const unsigned short* gk = Kbase + (size_t)(tc + (cl >> 4)) * EMB
                                     + (((cl & 15) ^ ((cl >> 4) & 7)) * 8);
            __builtin_amdgcn_global_load_lds(
                (const __attribute__((address_space(1))) void*)gk,
                (__attribute__((address_space(3))) void*)&Ks[(it*256 + w*64) * 8], 16, 0, 0);
            const unsigned short* gv = Vbase + (size_t)(cl >> 3) * SEQ + tc
                                     + (((cl & 7) ^ ((cl >> 3) & 7)) * 8);
            __builtin_amdgcn_global_load_lds(
                (const __attribute__((address_space(1))) void*)gv,
                (__attribute__((address_space(3))) void*)&Vs[(it*256 + w*64) * 8], 16, 0, 0);
        }
        __syncthreads();                              // vmcnt drained by compiler

        // ---- QK^T swapped from LDS: sc[kt][j] = S[key = tc+kt*16+g*4+j][q]
        f32x4 sc[4];
        #pragma unroll
        for (int kt = 0; kt < 4; ++kt) {
            sc[kt] = (f32x4){0.f, 0.f, 0.f, 0.f};
            if (tc + kt*16 <= qmaxw) {               // wave-uniform skip
                #pragma unroll
                for (int dch = 0; dch < 4; ++dch) {
                    bf16x8 kf = *(const bf16x8*)&Ks[(kt*16 + c)*128 + (((dch*4 + g) ^ (c & 7)) * 8)];
                    sc[kt] = __builtin_amdgcn_mfma_f32_16x16x32_bf16(kf, qf[dch], sc[kt], 0, 0, 0);
                }
            }
        }
        // ---- row max (lane-local over 16 vals + 2 shfl across g-groups)
        float mx = -1e30f;
        #pragma unroll
        for (int kt = 0; kt < 4; ++kt)
            #pragma unroll
            for (int j = 0; j < 4; ++j) {
                const int key = tc + kt*16 + g*4 + j;
                const float s = (key <= q) ? sc[kt][j] * scale : -1e30f;
                mx = fmaxf(mx, s);
            }
        mx = fmaxf(mx, __shfl_xor(mx, 16));
        mx = fmaxf(mx, __shfl_xor(mx, 32));
        // ---- defer-max rescale (T13, THR=8)
        if (!__all(mx <= m_c + 8.f)) {
            const float mn = fmaxf(m_c, mx);
            const float corr = __expf(m_c - mn);
            l_c *= corr;
            m_c = mn;
            #pragma unroll
            for (int j = 0; j < 4; ++j) {
                const float cj = __shfl(corr, g*4 + j);   // corr of query row g*4+j
                #pragma unroll
                for (int ni = 0; ni < 8; ++ni) o[ni][j] *= cj;
            }
        }
        // ---- P = exp(S - m), pack 4 bf16 -> LDS (8B writes), row sum
        float ps = 0.f;
        #pragma unroll
        for (int kt = 0; kt < 4; ++kt) {
            float p[4];
            #pragma unroll
            for (int j = 0; j < 4; ++j) {
                const int key = tc + kt*16 + g*4 + j;
                const float s = (key <= q) ? sc[kt][j] * scale : -1e30f;
                p[j] = __expf(s - m_c);
                ps += p[j];
            }
            uint2 pk;
            pk.x = (unsigned int)f2bf(p[0]) | ((unsigned int)f2bf(p[1]) << 16);
            pk.y = (unsigned int)f2bf(p[2]) | ((unsigned int)f2bf(p[3]) << 16);
            const int byte = (c*128 + kt*32 + g*8) ^ ((c & 7) << 4);
            *(uint2*)(pw + byte) = pk;
        }
        ps += __shfl_xor(ps, 16);
        ps += __shfl_xor(ps, 32);
        l_c += ps;
        asm volatile("s_waitcnt lgkmcnt(0)" ::: "memory");
        __builtin_amdgcn_sched_barrier(0);
        // ---- PV: A = P (row q=c from swizzled LDS), B = V^T from LDS
        #pragma unroll
        for (int kc = 0; kc < 2; ++kc) {
            if (tc + kc*32 <= qmaxw) {               // wave-uniform
                const int byte = (c*128 + kc*64 + g*16) ^ ((c & 7) << 4);
                bf16x8 pa = *(const bf16x8*)(pw + byte);
                #pragma unroll
                for (int ni = 0; ni < 8; ++ni) {
                    bf16x8 vf = *(const bf16x8*)&Vs[(ni*16 + c)*64 + (((kc*4 + g) ^ (c & 7)) * 8)];
                    o[ni] = __builtin_amdgcn_mfma_f32_16x16x32_bf16(pa, vf, o[ni], 0, 0, 0);
                }
            }
        }
        __syncthreads();                              // before next stage overwrites
    }

    // ---- epilogue: store unnormalized partial + (m, l)
    const int slot = ((b*NH + h) * 32 + qt) * 4 + ks;
    float* op = Opart + (size_t)slot * (64 * 128);
    #pragma unroll
    for (int ni = 0; ni < 8; ++ni)
        #pragma unroll
        for (int j = 0; j < 4; ++j)
            op[(size_t)(w*16 + g*4 + j) * 128 + ni*16 + c] = o[ni][j];
    if (lane < 16) {
        Ml[(size_t)slot * 128 +      w*16 + lane] = m_c;
        Ml[(size_t)slot * 128 + 64 + w*16 + lane] = l_c;
    }
}

// ------------- combine KV-split partials (4 slots) -> bf16 ctx ---------------
__global__ __launch_bounds__(256) void k_attn_reduce(const float* __restrict__ Opart,
                                                     const float* __restrict__ Ml,
                                                     unsigned short* __restrict__ Ob) {
    const int qt = blockIdx.x, h = blockIdx.y, b = blockIdx.z;
    const int slot0 = ((b*NH + h) * 32 + qt) * 4;
    const int row = threadIdx.x >> 2;
    const int c0 = (threadIdx.x & 3) * 32;
    float M = -1e30f;
    #pragma unroll
    for (int s = 0; s < 4; ++s)
        M = fmaxf(M, Ml[(size_t)(slot0 + s) * 128 + row]);
    float L = 0.f;
    float wgt[4];
    #pragma unroll
    for (int s = 0; s < 4; ++s) {
        wgt[s] = __expf(Ml[(size_t)(slot0 + s) * 128 + row] - M);
        L += Ml[(size_t)(slot0 + s) * 128 + 64 + row] * wgt[s];
    }
    float acc[32];
    #pragma unroll
    for (int k = 0; k < 32; ++k) acc[k] = 0.f;
    #pragma unroll
    for (int s = 0; s < 4; ++s) {
        const float4* op = (const float4*)(Opart + ((size_t)(slot0 + s) * 64 + row) * 128 + c0);
        #pragma unroll
        for (int q4 = 0; q4 < 8; ++q4) {
            float4 v = op[q4];
            acc[q4*4+0] += v.x * wgt[s]; acc[q4*4+1] += v.y * wgt[s];
            acc[q4*4+2] += v.z * wgt[s]; acc[q4*4+3] += v.w * wgt[s];
        }
    }
    const float inv = 1.0f / L;
    unsigned short* orow = Ob + (size_t)(b*SEQ + qt*64 + row) * EMB + h*HD + c0;
    #pragma unroll
    for (int q4 = 0; q4 < 8; ++q4) {
        ushort4 u;
        u.x = f2bf(acc[q4*4+0] * inv); u.y = f2bf(acc[q4*4+1] * inv);
        u.z = f2bf(acc[q4*4+2] * inv); u.w = f2bf(acc[q4*4+3] * inv);
        ((ushort4*)orow)[q4] = u;
    }
}

// ---------------- row LayerNorm over 2048, optional bf16 copy ---------------
__global__ __launch_bounds__(256) void k_ln(const float* __restrict__ X,
                                            const float* __restrict__ g,
                                            const float* __restrict__ be,
                                            float* __restrict__ Of32,
                                            unsigned short* __restrict__ Obf16) {
    const int row = blockIdx.x;
    const float* x = X + (size_t)row * EMB;
    float4 v[2];
    float s = 0.f, ss = 0.f;
    #pragma unroll
    for (int i = 0; i < 2; ++i) {
        v[i] = ((const float4*)x)[threadIdx.x + i*256];
        s  += v[i].x + v[i].y + v[i].z + v[i].w;
        ss += v[i].x*v[i].x + v[i].y*v[i].y + v[i].z*v[i].z + v[i].w*v[i].w;
    }
    #pragma unroll
    for (int o = 32; o; o >>= 1) { s += __shfl_xor(s, o); ss += __shfl_xor(ss, o); }
    __shared__ float red[2][4];
    const int lane = threadIdx.x & 63, wid = threadIdx.x >> 6;
    if (lane == 0) { red[0][wid] = s; red[1][wid] = ss; }
    __syncthreads();
    s  = red[0][0] + red[0][1] + red[0][2] + red[0][3];
    ss = red[1][0] + red[1][1] + red[1][2] + red[1][3];
    const float mu = s * (1.0f / EMB);
    const float var = ss * (1.0f / EMB) - mu * mu;
    const float rs = rsqrtf(var + 1e-5f);
    #pragma unroll
    for (int i = 0; i < 2; ++i) {
        const int c4 = threadIdx.x + i*256;
        float4 gv = ((const float4*)g)[c4];
        float4 bv = ((const float4*)be)[c4];
        float4 y;
        y.x = (v[i].x - mu) * rs * gv.x + bv.x;
        y.y = (v[i].y - mu) * rs * gv.y + bv.y;
        y.z = (v[i].z - mu) * rs * gv.z + bv.z;
        y.w = (v[i].w - mu) * rs * gv.w + bv.w;
        if (Of32)  ((float4*)(Of32 + (size_t)row * EMB))[c4] = y;
        if (Obf16) {
            ushort4 u; u.x = f2bf(y.x); u.y = f2bf(y.y); u.z = f2bf(y.z); u.w = f2bf(y.w);
            ((ushort4*)(Obf16 + (size_t)row * EMB))[c4] = u;
        }
    }
}

extern "C" void kernel_launch(void* const* d_in, const int* in_sizes, int n_in,
                              void* d_out, int out_size, void* d_ws, size_t ws_size,
                              hipStream_t stream) {
    const float* emb = (const float*)d_in[0];
    const float* Wq  = (const float*)d_in[1];  const float* bq  = (const float*)d_in[2];
    const float* Wk  = (const float*)d_in[3];  const float* bk  = (const float*)d_in[4];
    const float* Wv  = (const float*)d_in[5];  const float* bv  = (const float*)d_in[6];
    const float* Wfc = (const float*)d_in[7];  const float* bfc = (const float*)d_in[8];
    const float* g1  = (const float*)d_in[9];  const float* be1 = (const float*)d_in[10];
    const float* W1  = (const float*)d_in[11]; const float* b1  = (const float*)d_in[12];
    const float* W2  = (const float*)d_in[13]; const float* b2  = (const float*)d_in[14];
    const float* g2  = (const float*)d_in[15]; const float* be2 = (const float*)d_in[16];

    // workspace layout (240 MB), lifetime-based reuse.  During attention the
    // regions of ln1B/x1f/ln1f/hB are dead -> partials overlap them.
    char* ws = (char*)d_ws;
    unsigned short* aB   = (unsigned short*)(ws + (size_t)(0  ) * (1u<<20)); // 16MB: emb bf16 -> ctx bf16
    unsigned short* ln1B = (unsigned short*)(ws + (size_t)(16 ) * (1u<<20)); // 16MB (after attn)
    float*          Ml   = (float*)         (ws + (size_t)(16 ) * (1u<<20)); // 2MB during attn (dead after)
    unsigned short* WtB  = (unsigned short*)(ws + (size_t)(32 ) * (1u<<20)); // 32MB transposed weight (serial reuse)
    unsigned short* Qb   = (unsigned short*)(ws + (size_t)(64 ) * (1u<<20)); // 16MB Q bf16
    unsigned short* Kb   = (unsigned short*)(ws + (size_t)(80 ) * (1u<<20)); // 16MB K bf16
    unsigned short* VTb  = (unsigned short*)(ws + (size_t)(96 ) * (1u<<20)); // 16MB V^T bf16 per head
    float*          x1f  = (float*)         (ws + (size_t)(112) * (1u<<20)); // 32MB x1 f32 (after attn)
    float*          Opart= (float*)         (ws + (size_t)(112) * (1u<<20)); // 128MB partials during attn
    float*          ln1f = (float*)         (ws + (size_t)(144) * (1u<<20)); // 32MB ln1 f32 (after attn)
    unsigned short* hB   = (unsigned short*)(ws + (size_t)(176) * (1u<<20)); // 64MB GELU(ffn1) bf16 (after attn)

    const dim3 blk(256);
    const dim3 blk2(512);
    const int n4 = MTOK * EMB / 4;

    // embeddings -> bf16
    k_conv<<<dim3(n4 / 256), blk, 0, stream>>>(emb, aB, n4);

    // Q, K projections (bf16 out), V projection (per-head transposed bf16 out)
    k_transconv<<<dim3(EMB/32, EMB/32), blk, 0, stream>>>(Wq, WtB, EMB, EMB);
    k_gemm2<128,3><<<dim3((MTOK/256)*(EMB/128)), blk2, 0, stream>>>(aB, WtB, bq, nullptr, Qb, MTOK, EMB, EMB);
    k_transconv<<<dim3(EMB/32, EMB/32), blk, 0, stream>>>(Wk, WtB, EMB, EMB);
    k_gemm2<128,3><<<dim3((MTOK/256)*(EMB/128)), blk2, 0, stream>>>(aB, WtB, bk, nullptr, Kb, MTOK, EMB, EMB);
    k_transconv<<<dim3(EMB/32, EMB/32), blk, 0, stream>>>(Wv, WtB, EMB, EMB);
    k_gemm2<128,4><<<dim3((MTOK/256)*(EMB/128)), blk2, 0, stream>>>(aB, WtB, bv, nullptr, VTb, MTOK, EMB, EMB);

    // KV-split MFMA flash attention -> partials -> ctx bf16 (overwrites aB)
    k_attn_part<<<dim3(4096), blk, 0, stream>>>(Qb, Kb, VTb, Opart, Ml);
    k_attn_reduce<<<dim3(SEQ/64, NH, BATCH), blk, 0, stream>>>(Opart, Ml, aB);

    // x1 = ctx@Wfc + bfc + emb -> x1f
    k_transconv<<<dim3(EMB/32, EMB/32), blk, 0, stream>>>(Wfc, WtB, EMB, EMB);
    k_gemm2<128,1><<<dim3((MTOK/256)*(EMB/128)), blk2, 0, stream>>>(aB, WtB, bfc, emb, x1f, MTOK, EMB, EMB);

    // LN1 -> f32 (ln1f) + bf16 (ln1B)
    k_ln<<<dim3(MTOK), blk, 0, stream>>>(x1f, g1, be1, ln1f, ln1B);

    // h = gelu(ln1 @ W1 + b1) -> bf16
    k_transconv<<<dim3(4*EMB/32, EMB/32), blk, 0, stream>>>(W1, WtB, EMB, 4*EMB);
    k_gemm2<256,2><<<dim3((MTOK/256)*((4*EMB)/256)), blk2, 0, stream>>>(ln1B, WtB, b1, nullptr, hB, MTOK, 4*EMB, EMB);

    // x2 = h @ W2 + b2 + ln1 -> d_out
    k_transconv<<<dim3(EMB/32, (4*EMB)/32), blk, 0, stream>>>(W2, WtB, 4*EMB, EMB);
    k_gemm2<128,1><<<dim3((MTOK/256)*(EMB/128)), blk2, 0, stream>>>(hB, WtB, b2, ln1f, (float*)d_out, MTOK, EMB, 4*EMB);

    // LN2 in-place on d_out
    k_ln<<<dim3(MTOK), blk, 0, stream>>>((const float*)d_out, g2, be2, (float*)d_out, nullptr);
}

// Round 7
// 818.430 us; speedup vs baseline: 1.4537x; 1.0597x over previous
//
#include <hip/hip_runtime.h>
#include <hip/hip_bf16.h>
#include <math.h>

#define EMB  2048
#define NH   16
#define HD   128
#define SEQ  2048
#define BATCH 2
#define MTOK (BATCH*SEQ)   // 4096 tokens

using bf16x8 = __attribute__((ext_vector_type(8))) __bf16;
using f32x4  = __attribute__((ext_vector_type(4))) float;

__device__ __forceinline__ unsigned short f2bf(float x) {
    unsigned int u = __float_as_uint(x);
    u += 0x7fffu + ((u >> 16) & 1u);   // round-to-nearest-even
    return (unsigned short)(u >> 16);
}

__device__ __forceinline__ float gelu_exact(float x) {
    return 0.5f * x * (1.0f + erff(x * 0.70710678118654752f));
}

// ---------------- flat f32 -> bf16 convert (4 elems/thread) ----------------
__global__ __launch_bounds__(256) void k_conv(const float* __restrict__ in,
                                              unsigned short* __restrict__ out, int n4) {
    int i = blockIdx.x * 256 + threadIdx.x;
    if (i >= n4) return;
    float4 v = ((const float4*)in)[i];
    ushort4 o;
    o.x = f2bf(v.x); o.y = f2bf(v.y); o.z = f2bf(v.z); o.w = f2bf(v.w);
    ((ushort4*)out)[i] = o;
}

// ------------- W[K][N] f32 -> Wt[N][K] bf16 (tiled transpose) ---------------
__global__ __launch_bounds__(256) void k_transconv(const float* __restrict__ W,
                                                   unsigned short* __restrict__ Wt,
                                                   int K, int N) {
    __shared__ float t[32][33];
    int tx = threadIdx.x & 31, ty = threadIdx.x >> 5;   // 32 x 8
    int c0 = blockIdx.x * 32, r0 = blockIdx.y * 32;
    #pragma unroll
    for (int i = 0; i < 4; ++i)
        t[ty + i*8][tx] = W[(size_t)(r0 + ty + i*8) * N + c0 + tx];
    __syncthreads();
    #pragma unroll
    for (int i = 0; i < 4; ++i)
        Wt[(size_t)(c0 + ty + i*8) * K + r0 + tx] = f2bf(t[tx][ty + i*8]);
}

// ------------- 256x256 deep-pipelined bf16 MFMA GEMM (m201 geometry) --------
// C = A[M,K] @ Bt[N,K]^T.  512 threads = 8 waves (2 wm x 4 wn), wave output
// 128x64.  BK=64, double-buffered LDS (128 KB), prefetch t+2 after compute
// barrier, counted vmcnt(8) in steady state (T3/T4), setprio around MFMA
// clusters (T5).  16B-chunk XOR swizzle, inverse pre-applied on global src.
// NSPLIT: split-K parts (grid = nmt*nnt*NSPLIT, partial kk -> C0 + kk*M*N).
// EPI: 2 = bf16 GELU(+bias); 5 = f32 partial (no bias); 6 = fused QKV
//      (C0=Q bf16, C1=K bf16, C2=V^T per-head bf16; bias = concat 6144)
template<int EPI, int NSPLIT>
__global__ __launch_bounds__(512, 1) void k_gemm3(const unsigned short* __restrict__ A,
                                                  const unsigned short* __restrict__ Bt,
                                                  const float* __restrict__ bias,
                                                  void* __restrict__ C0,
                                                  void* __restrict__ C1,
                                                  void* __restrict__ C2,
                                                  int M, int N, int Kred, int ldk) {
    __shared__ unsigned short As[2][256 * 64];
    __shared__ unsigned short Bs[2][256 * 64];
    const int tid = threadIdx.x, lane = tid & 63, wid = tid >> 6;
    const int wm = wid >> 2, wn = wid & 3;              // 2 x 4 waves
    const int nmt = M >> 8, nnt = N >> 8;
    const int nblk = nmt * nnt * NSPLIT, cpx = nblk >> 3;
    const int swz = (blockIdx.x & 7) * cpx + (blockIdx.x >> 3);   // XCD-chunked
    const int bm = swz % nmt;
    const int t2 = swz / nmt;
    const int bn = t2 % nnt, kk = t2 / nnt;
    const unsigned short* Ab = A  + (size_t)bm * 256 * ldk + (size_t)kk * Kred;
    const unsigned short* Bb = Bt + (size_t)bn * 256 * ldk + (size_t)kk * Kred;

    auto STAGE = [&](int ti, int bbuf) {
        const int kt = ti * 64;
        #pragma unroll
        for (int it = 0; it < 4; ++it) {
            const int slot = it * 512 + tid;
            const int r = slot >> 3, cs = slot & 7;
            const unsigned short* ga = Ab + (size_t)r * ldk + kt + ((cs ^ (r & 7)) * 8);
            __builtin_amdgcn_global_load_lds(
                (const __attribute__((address_space(1))) void*)ga,
                (__attribute__((address_space(3))) void*)&As[bbuf][(it*512 + wid*64) * 8], 16, 0, 0);
            const unsigned short* gb = Bb + (size_t)r * ldk + kt + ((cs ^ (r & 7)) * 8);
            __builtin_amdgcn_global_load_lds(
                (const __attribute__((address_space(1))) void*)gb,
                (__attribute__((address_space(3))) void*)&Bs[bbuf][(it*512 + wid*64) * 8], 16, 0, 0);
        }
    };

    f32x4 acc[8][4] = {};
    const int NT = Kred >> 6;
    STAGE(0, 0);
    STAGE(1, 1);

    for (int t = 0; t < NT; ++t) {
        const int bb = t & 1;
        if (t == NT - 1) asm volatile("s_waitcnt vmcnt(0)" ::: "memory");
        else             asm volatile("s_waitcnt vmcnt(8)" ::: "memory");
        __builtin_amdgcn_s_barrier();
        __builtin_amdgcn_sched_barrier(0);

        #pragma unroll
        for (int kh = 0; kh < 2; ++kh) {
            bf16x8 af[8], bfr[4];
            #pragma unroll
            for (int mi = 0; mi < 8; ++mi)
                af[mi] = *(const bf16x8*)&As[bb][(wm*128 + mi*16 + (lane & 15))*64
                                                + (((kh*4 + (lane >> 4)) ^ (lane & 7)) * 8)];
            #pragma unroll
            for (int ni = 0; ni < 4; ++ni)
                bfr[ni] = *(const bf16x8*)&Bs[bb][(wn*64 + ni*16 + (lane & 15))*64
                                                 + (((kh*4 + (lane >> 4)) ^ (lane & 7)) * 8)];
            __builtin_amdgcn_s_setprio(1);
            #pragma unroll
            for (int mi = 0; mi < 8; ++mi)
                #pragma unroll
                for (int ni = 0; ni < 4; ++ni)
                    acc[mi][ni] = __builtin_amdgcn_mfma_f32_16x16x32_bf16(af[mi], bfr[ni], acc[mi][ni], 0, 0, 0);
            __builtin_amdgcn_s_setprio(0);
            __builtin_amdgcn_sched_barrier(0);
        }

        __builtin_amdgcn_s_barrier();
        __builtin_amdgcn_sched_barrier(0);
        if (t + 2 < NT) STAGE(t + 2, bb);
    }

    const int row0b = bm*256 + wm*128, col0 = bn*256 + wn*64;
    #pragma unroll
    for (int mi = 0; mi < 8; ++mi) {
        #pragma unroll
        for (int ni = 0; ni < 4; ++ni) {
            const int c = col0 + ni*16 + (lane & 15);
            const int r0 = row0b + mi*16 + (lane >> 4) * 4;
            if (EPI == 5) {
                float* out = (float*)C0 + (size_t)kk * M * N;
                #pragma unroll
                for (int j = 0; j < 4; ++j)
                    out[(size_t)(r0+j) * N + c] = acc[mi][ni][j];
            } else if (EPI == 2) {
                const float bv = bias[c];
                #pragma unroll
                for (int j = 0; j < 4; ++j)
                    ((unsigned short*)C0)[(size_t)(r0+j) * N + c] = f2bf(gelu_exact(acc[mi][ni][j] + bv));
            } else {  // EPI == 6: fused QKV epilogue
                const float bv = bias[c];
                const int seg = c >> 11;           // 0=Q, 1=K, 2=V (uniform per ni)
                if (seg == 0) {
                    #pragma unroll
                    for (int j = 0; j < 4; ++j)
                        ((unsigned short*)C0)[(size_t)(r0+j) * EMB + c] = f2bf(acc[mi][ni][j] + bv);
                } else if (seg == 1) {
                    #pragma unroll
                    for (int j = 0; j < 4; ++j)
                        ((unsigned short*)C1)[(size_t)(r0+j) * EMB + (c - 2048)] = f2bf(acc[mi][ni][j] + bv);
                } else {
                    const int cc = c - 4096;
                    const int hh = cc >> 7, dd = cc & 127;
                    const int bb2 = r0 >> 11, s0 = r0 & 2047;
                    ushort4 u;
                    u.x = f2bf(acc[mi][ni][0] + bv); u.y = f2bf(acc[mi][ni][1] + bv);
                    u.z = f2bf(acc[mi][ni][2] + bv); u.w = f2bf(acc[mi][ni][3] + bv);
                    *(ushort4*)((unsigned short*)C2 +
                                ((size_t)((bb2*NH + hh)*HD + dd) * SEQ + s0)) = u;
                }
            }
        }
    }
}

// ------------- MFMA flash attention, KV-split partials (bf16, causal) -------
__global__ __launch_bounds__(256, 4) void k_attn_part(const unsigned short* __restrict__ Qb,
                                                      const unsigned short* __restrict__ Kb,
                                                      const unsigned short* __restrict__ VTb,
                                                      float* __restrict__ Opart,
                                                      float* __restrict__ Ml) {
    const int tid = threadIdx.x;
    const int lane = tid & 63, w = tid >> 6;
    const int g = lane >> 4, c = lane & 15;
    const int bid = blockIdx.x;
    const int swz = (bid & 7) * 512 + (bid >> 3);
    const int bh = swz >> 7;
    const int b = bh >> 4, h = bh & 15;
    const int rr = swz & 127;
    const int qt = rr >> 2, ks = rr & 3;
    const int nt = qt + 1;
    const int t0 = (nt * ks) >> 2, t1 = (nt * (ks + 1)) >> 2;
    const int qb = qt * 64 + w * 16;

    __shared__ unsigned short Ks[64 * 128];
    __shared__ unsigned short Vs[128 * 64];
    __shared__ unsigned short p_lds[4][16 * 64];

    bf16x8 qf[4];
    {
        const unsigned short* qrow = Qb + (size_t)(b*SEQ + qb + c) * EMB + h*HD;
        #pragma unroll
        for (int dch = 0; dch < 4; ++dch)
            qf[dch] = *(const bf16x8*)(qrow + dch*32 + g*8);
    }

    f32x4 o[8];
    #pragma unroll
    for (int ni = 0; ni < 8; ++ni) o[ni] = (f32x4){0.f, 0.f, 0.f, 0.f};
    float m_c = -1e30f, l_c = 0.f;

    const int q = qb + c;
    const int qmaxw = qb + 15;
    const unsigned short* Kbase = Kb  + (size_t)(b*SEQ) * EMB + h*HD;
    const unsigned short* Vbase = VTb + (size_t)((b*NH + h) * HD) * SEQ;
    const float scale = 0.08838834764831845f;
    char* pw = (char*)&p_lds[w][0];

    for (int ti = t0; ti < t1; ++ti) {
        const int tc = ti * 64;
        #pragma unroll
        for (int it = 0; it < 4; ++it) {
            const int cl = it * 256 + tid;
            const unsigned short* gk = Kbase + (size_t)(tc + (cl >> 4)) * EMB
                                     + (((cl & 15) ^ ((cl >> 4) & 7)) * 8);
            __builtin_amdgcn_global_load_lds(
                (const __attribute__((address_space(1))) void*)gk,
                (__attribute__((address_space(3))) void*)&Ks[(it*256 + w*64) * 8], 16, 0, 0);
            const unsigned short* gv = Vbase + (size_t)(cl >> 3) * SEQ + tc
                                     + (((cl & 7) ^ ((cl >> 3) & 7)) * 8);
            __builtin_amdgcn_global_load_lds(
                (const __attribute__((address_space(1))) void*)gv,
                (__attribute__((address_space(3))) void*)&Vs[(it*256 + w*64) * 8], 16, 0, 0);
        }
        __syncthreads();

        f32x4 sc[4];
        #pragma unroll
        for (int kt = 0; kt < 4; ++kt) {
            sc[kt] = (f32x4){0.f, 0.f, 0.f, 0.f};
            if (tc + kt*16 <= qmaxw) {
                #pragma unroll
                for (int dch = 0; dch < 4; ++dch) {
                    bf16x8 kf = *(const bf16x8*)&Ks[(kt*16 + c)*128 + (((dch*4 + g) ^ (c & 7)) * 8)];
                    sc[kt] = __builtin_amdgcn_mfma_f32_16x16x32_bf16(kf, qf[dch], sc[kt], 0, 0, 0);
                }
            }
        }
        float mx = -1e30f;
        #pragma unroll
        for (int kt = 0; kt < 4; ++kt)
            #pragma unroll
            for (int j = 0; j < 4; ++j) {
                const int key = tc + kt*16 + g*4 + j;
                const float s = (key <= q) ? sc[kt][j] * scale : -1e30f;
                mx = fmaxf(mx, s);
            }
        mx = fmaxf(mx, __shfl_xor(mx, 16));
        mx = fmaxf(mx, __shfl_xor(mx, 32));
        if (!__all(mx <= m_c + 8.f)) {
            const float mn = fmaxf(m_c, mx);
            const float corr = __expf(m_c - mn);
            l_c *= corr;
            m_c = mn;
            #pragma unroll
            for (int j = 0; j < 4; ++j) {
                const float cj = __shfl(corr, g*4 + j);
                #pragma unroll
                for (int ni = 0; ni < 8; ++ni) o[ni][j] *= cj;
            }
        }
        float ps = 0.f;
        #pragma unroll
        for (int kt = 0; kt < 4; ++kt) {
            float p[4];
            #pragma unroll
            for (int j = 0; j < 4; ++j) {
                const int key = tc + kt*16 + g*4 + j;
                const float s = (key <= q) ? sc[kt][j] * scale : -1e30f;
                p[j] = __expf(s - m_c);
                ps += p[j];
            }
            uint2 pk;
            pk.x = (unsigned int)f2bf(p[0]) | ((unsigned int)f2bf(p[1]) << 16);
            pk.y = (unsigned int)f2bf(p[2]) | ((unsigned int)f2bf(p[3]) << 16);
            const int byte = (c*128 + kt*32 + g*8) ^ ((c & 7) << 4);
            *(uint2*)(pw + byte) = pk;
        }
        ps += __shfl_xor(ps, 16);
        ps += __shfl_xor(ps, 32);
        l_c += ps;
        asm volatile("s_waitcnt lgkmcnt(0)" ::: "memory");
        __builtin_amdgcn_sched_barrier(0);
        #pragma unroll
        for (int kc = 0; kc < 2; ++kc) {
            if (tc + kc*32 <= qmaxw) {
                const int byte = (c*128 + kc*64 + g*16) ^ ((c & 7) << 4);
                bf16x8 pa = *(const bf16x8*)(pw + byte);
                #pragma unroll
                for (int ni = 0; ni < 8; ++ni) {
                    bf16x8 vf = *(const bf16x8*)&Vs[(ni*16 + c)*64 + (((kc*4 + g) ^ (c & 7)) * 8)];
                    o[ni] = __builtin_amdgcn_mfma_f32_16x16x32_bf16(pa, vf, o[ni], 0, 0, 0);
                }
            }
        }
        __syncthreads();
    }

    const int slot = ((b*NH + h) * 32 + qt) * 4 + ks;
    float* op = Opart + (size_t)slot * (64 * 128);
    #pragma unroll
    for (int ni = 0; ni < 8; ++ni)
        #pragma unroll
        for (int j = 0; j < 4; ++j)
            op[(size_t)(w*16 + g*4 + j) * 128 + ni*16 + c] = o[ni][j];
    if (lane < 16) {
        Ml[(size_t)slot * 128 +      w*16 + lane] = m_c;
        Ml[(size_t)slot * 128 + 64 + w*16 + lane] = l_c;
    }
}

// ------------- combine KV-split partials (4 slots) -> bf16 ctx ---------------
__global__ __launch_bounds__(256) void k_attn_reduce(const float* __restrict__ Opart,
                                                     const float* __restrict__ Ml,
                                                     unsigned short* __restrict__ Ob) {
    const int qt = blockIdx.x, h = blockIdx.y, b = blockIdx.z;
    const int slot0 = ((b*NH + h) * 32 + qt) * 4;
    const int row = threadIdx.x >> 2;
    const int c0 = (threadIdx.x & 3) * 32;
    float M = -1e30f;
    #pragma unroll
    for (int s = 0; s < 4; ++s)
        M = fmaxf(M, Ml[(size_t)(slot0 + s) * 128 + row]);
    float L = 0.f;
    float wgt[4];
    #pragma unroll
    for (int s = 0; s < 4; ++s) {
        wgt[s] = __expf(Ml[(size_t)(slot0 + s) * 128 + row] - M);
        L += Ml[(size_t)(slot0 + s) * 128 + 64 + row] * wgt[s];
    }
    float acc[32];
    #pragma unroll
    for (int k = 0; k < 32; ++k) acc[k] = 0.f;
    #pragma unroll
    for (int s = 0; s < 4; ++s) {
        const float4* op = (const float4*)(Opart + ((size_t)(slot0 + s) * 64 + row) * 128 + c0);
        #pragma unroll
        for (int q4 = 0; q4 < 8; ++q4) {
            float4 v = op[q4];
            acc[q4*4+0] += v.x * wgt[s]; acc[q4*4+1] += v.y * wgt[s];
            acc[q4*4+2] += v.z * wgt[s]; acc[q4*4+3] += v.w * wgt[s];
        }
    }
    const float inv = 1.0f / L;
    unsigned short* orow = Ob + (size_t)(b*SEQ + qt*64 + row) * EMB + h*HD + c0;
    #pragma unroll
    for (int q4 = 0; q4 < 8; ++q4) {
        ushort4 u;
        u.x = f2bf(acc[q4*4+0] * inv); u.y = f2bf(acc[q4*4+1] * inv);
        u.z = f2bf(acc[q4*4+2] * inv); u.w = f2bf(acc[q4*4+3] * inv);
        ((ushort4*)orow)[q4] = u;
    }
}

// ------- row LayerNorm over 2048 with fused input combine -------------------
// x = X0 (+X1) (+bias) (+res); y = LN(x)*g + be -> Of32 / Obf16 (nullable)
__global__ __launch_bounds__(256) void k_ln(const float* __restrict__ X0,
                                            const float* __restrict__ X1,
                                            const float* __restrict__ bias,
                                            const float* __restrict__ res,
                                            const float* __restrict__ g,
                                            const float* __restrict__ be,
                                            float* __restrict__ Of32,
                                            unsigned short* __restrict__ Obf16) {
    const int row = blockIdx.x;
    float4 v[2];
    float s = 0.f, ss = 0.f;
    #pragma unroll
    for (int i = 0; i < 2; ++i) {
        const int c4 = threadIdx.x + i*256;
        float4 a = ((const float4*)(X0 + (size_t)row * EMB))[c4];
        if (X1) {
            float4 b1v = ((const float4*)(X1 + (size_t)row * EMB))[c4];
            a.x += b1v.x; a.y += b1v.y; a.z += b1v.z; a.w += b1v.w;
        }
        if (bias) {
            float4 bv = ((const float4*)bias)[c4];
            a.x += bv.x; a.y += bv.y; a.z += bv.z; a.w += bv.w;
        }
        if (res) {
            float4 rv = ((const float4*)(res + (size_t)row * EMB))[c4];
            a.x += rv.x; a.y += rv.y; a.z += rv.z; a.w += rv.w;
        }
        v[i] = a;
        s  += a.x + a.y + a.z + a.w;
        ss += a.x*a.x + a.y*a.y + a.z*a.z + a.w*a.w;
    }
    #pragma unroll
    for (int o = 32; o; o >>= 1) { s += __shfl_xor(s, o); ss += __shfl_xor(ss, o); }
    __shared__ float red[2][4];
    const int lane = threadIdx.x & 63, wid = threadIdx.x >> 6;
    if (lane == 0) { red[0][wid] = s; red[1][wid] = ss; }
    __syncthreads();
    s  = red[0][0] + red[0][1] + red[0][2] + red[0][3];
    ss = red[1][0] + red[1][1] + red[1][2] + red[1][3];
    const float mu = s * (1.0f / EMB);
    const float var = ss * (1.0f / EMB) - mu * mu;
    const float rs = rsqrtf(var + 1e-5f);
    #pragma unroll
    for (int i = 0; i < 2; ++i) {
        const int c4 = threadIdx.x + i*256;
        float4 gv = ((const float4*)g)[c4];
        float4 bv = ((const float4*)be)[c4];
        float4 y;
        y.x = (v[i].x - mu) * rs * gv.x + bv.x;
        y.y = (v[i].y - mu) * rs * gv.y + bv.y;
        y.z = (v[i].z - mu) * rs * gv.z + bv.z;
        y.w = (v[i].w - mu) * rs * gv.w + bv.w;
        if (Of32)  ((float4*)(Of32 + (size_t)row * EMB))[c4] = y;
        if (Obf16) {
            ushort4 u; u.x = f2bf(y.x); u.y = f2bf(y.y); u.z = f2bf(y.z); u.w = f2bf(y.w);
            ((ushort4*)(Obf16 + (size_t)row * EMB))[c4] = u;
        }
    }
}

extern "C" void kernel_launch(void* const* d_in, const int* in_sizes, int n_in,
                              void* d_out, int out_size, void* d_ws, size_t ws_size,
                              hipStream_t stream) {
    const float* emb = (const float*)d_in[0];
    const float* Wq  = (const float*)d_in[1];  const float* bq  = (const float*)d_in[2];
    const float* Wk  = (const float*)d_in[3];  const float* bk  = (const float*)d_in[4];
    const float* Wv  = (const float*)d_in[5];  const float* bv  = (const float*)d_in[6];
    const float* Wfc = (const float*)d_in[7];  const float* bfc = (const float*)d_in[8];
    const float* g1  = (const float*)d_in[9];  const float* be1 = (const float*)d_in[10];
    const float* W1  = (const float*)d_in[11]; const float* b1  = (const float*)d_in[12];
    const float* W2  = (const float*)d_in[13]; const float* b2  = (const float*)d_in[14];
    const float* g2  = (const float*)d_in[15]; const float* be2 = (const float*)d_in[16];

    // workspace layout (240 MB max), lifetime-based reuse:
    //  [0,16)   aB: emb bf16 -> ctx bf16
    //  [16,32)  ln1B
    //  [32,64)  WtB (serial per-GEMM); [32,34) Ml during attention (WtB dead)
    //  [64,128) hB (W1 out); [64,80)/[80,96)/[96,112) Qb/Kb/VTb during attn
    //  [112,240) Opart during attention
    //  [128,160) pA, [160,192) pB  (split-K partials; after attn)
    //  [192,224) ln1f
    //  [236,237) bias6 (QKV fused bias; dead before Opart written)
    char* ws = (char*)d_ws;
    unsigned short* aB   = (unsigned short*)(ws + (size_t)  0 * (1u<<20));
    unsigned short* ln1B = (unsigned short*)(ws + (size_t) 16 * (1u<<20));
    unsigned short* WtB  = (unsigned short*)(ws + (size_t) 32 * (1u<<20));
    float*          Ml   = (float*)         (ws + (size_t) 32 * (1u<<20));
    unsigned short* hB   = (unsigned short*)(ws + (size_t) 64 * (1u<<20));
    unsigned short* Qb   = (unsigned short*)(ws + (size_t) 64 * (1u<<20));
    unsigned short* Kb   = (unsigned short*)(ws + (size_t) 80 * (1u<<20));
    unsigned short* VTb  = (unsigned short*)(ws + (size_t) 96 * (1u<<20));
    float*          Opart= (float*)         (ws + (size_t)112 * (1u<<20));
    float*          pA   = (float*)         (ws + (size_t)128 * (1u<<20));
    float*          ln1f = (float*)         (ws + (size_t)192 * (1u<<20));
    float*          bias6= (float*)         (ws + (size_t)236 * (1u<<20));

    const dim3 blk(256);
    const dim3 blk2(512);
    const int n4 = MTOK * EMB / 4;

    // embeddings -> bf16; assemble fused QKV bias
    k_conv<<<dim3(n4 / 256), blk, 0, stream>>>(emb, aB, n4);
    hipMemcpyAsync(bias6,        bq, EMB*sizeof(float), hipMemcpyDeviceToDevice, stream);
    hipMemcpyAsync(bias6 + EMB,  bk, EMB*sizeof(float), hipMemcpyDeviceToDevice, stream);
    hipMemcpyAsync(bias6 + 2*EMB,bv, EMB*sizeof(float), hipMemcpyDeviceToDevice, stream);

    // fused QKV: Wt = [6144][2048]
    k_transconv<<<dim3(EMB/32, EMB/32), blk, 0, stream>>>(Wq, WtB,              EMB, EMB);
    k_transconv<<<dim3(EMB/32, EMB/32), blk, 0, stream>>>(Wk, WtB + EMB*EMB,    EMB, EMB);
    k_transconv<<<dim3(EMB/32, EMB/32), blk, 0, stream>>>(Wv, WtB + 2*EMB*EMB,  EMB, EMB);
    k_gemm3<6,1><<<dim3((MTOK/256)*(3*EMB/256)), blk2, 0, stream>>>(
        aB, WtB, bias6, Qb, Kb, VTb, MTOK, 3*EMB, EMB, EMB);

    // KV-split MFMA flash attention -> partials -> ctx bf16 (overwrites aB)
    k_attn_part<<<dim3(4096), blk, 0, stream>>>(Qb, Kb, VTb, Opart, Ml);
    k_attn_reduce<<<dim3(SEQ/64, NH, BATCH), blk, 0, stream>>>(Opart, Ml, aB);

    // Wfc split-K x2 -> pA/pB; LN1 fuses +bfc+emb
    k_transconv<<<dim3(EMB/32, EMB/32), blk, 0, stream>>>(Wfc, WtB, EMB, EMB);
    k_gemm3<5,2><<<dim3((MTOK/256)*(EMB/256)*2), blk2, 0, stream>>>(
        aB, WtB, nullptr, pA, nullptr, nullptr, MTOK, EMB, EMB/2, EMB);
    k_ln<<<dim3(MTOK), blk, 0, stream>>>(pA, pA + (size_t)MTOK*EMB, bfc, emb, g1, be1, ln1f, ln1B);

    // h = gelu(ln1 @ W1 + b1) -> hB
    k_transconv<<<dim3(4*EMB/32, EMB/32), blk, 0, stream>>>(W1, WtB, EMB, 4*EMB);
    k_gemm3<2,1><<<dim3((MTOK/256)*(4*EMB/256)), blk2, 0, stream>>>(
        ln1B, WtB, b1, hB, nullptr, nullptr, MTOK, 4*EMB, EMB, EMB);

    // W2 split-K x2 -> pA/pB; LN2 fuses +b2+ln1f -> d_out
    k_transconv<<<dim3(EMB/32, (4*EMB)/32), blk, 0, stream>>>(W2, WtB, 4*EMB, EMB);
    k_gemm3<5,2><<<dim3((MTOK/256)*(EMB/256)*2), blk2, 0, stream>>>(
        hB, WtB, nullptr, pA, nullptr, nullptr, MTOK, EMB, 2*EMB, 4*EMB);
    k_ln<<<dim3(MTOK), blk, 0, stream>>>(pA, pA + (size_t)MTOK*EMB, b2, ln1f, g2, be2, (float*)d_out, nullptr);
}